// Round 16
// baseline (244.684 us; speedup 1.0000x reference)
//
#include <hip/hip_runtime.h>

#define D_SZ 768
#define N_SZ 50000
#define L_SZ 28
#define B_SZ 1024
#define NP2  50176   // 392*128 (padded N); 392 = 98*4 exactly

#define CONV_BLK 19488   // (NP2 + B_SZ + D_SZ) * 96 / 256
#define EXCT_BLK 784     // NP2 / 64

typedef float f32x4 __attribute__((ext_vector_type(4)));
typedef float f32x16 __attribute__((ext_vector_type(16)));
typedef int i32x8 __attribute__((ext_vector_type(8)));

// byte-order-proof single fp8 e4m3 convert (both packed bytes equal)
__device__ __forceinline__ unsigned char f2fp8(float a) {
  unsigned r;
  asm("v_cvt_pk_fp8_f32 %0, %1, %2" : "=v"(r) : "v"(a), "v"(a));
  return (unsigned char)(r & 0xFF);
}
__device__ __forceinline__ unsigned pk4_fp8(float a, float b, float c, float d) {
  unsigned lo, hi;
  asm("v_cvt_pk_fp8_f32 %0, %1, %2" : "=v"(lo) : "v"(a), "v"(b));
  asm("v_cvt_pk_fp8_f32 %0, %1, %2" : "=v"(hi) : "v"(c), "v"(d));
  return (lo & 0xFFFFu) | (hi << 16);
}
// exact fp8 e4m3 -> f32 (bit math; no NaN inputs occur here)
__device__ __forceinline__ float fp82f(unsigned b) {
  const int e = (b >> 3) & 15, mnt = b & 7;
  const float mag = ldexpf((float)(e ? mnt + 8 : mnt), (e ? e : 1) - 10);
  return (b & 0x80) ? -mag : mag;
}
__device__ __forceinline__ i32x8 mk8(uint4 lo, uint4 hi) {
  i32x8 r;
  r[0] = (int)lo.x; r[1] = (int)lo.y; r[2] = (int)lo.z; r[3] = (int)lo.w;
  r[4] = (int)hi.x; r[5] = (int)hi.y; r[6] = (int)hi.z; r[7] = (int)hi.w;
  return r;
}
#define MFMA16(a, b, c) \
  __builtin_amdgcn_mfma_scale_f32_16x16x128_f8f6f4((a), (b), (c), 0, 0, \
                                                   0, 0x7F7F7F7F, 0, 0x7F7F7F7F)
#define MFMA32(a, b, c) \
  __builtin_amdgcn_mfma_scale_f32_32x32x64_f8f6f4((a), (b), (c), 0, 0, \
                                                  0, 0x7F7F7F7F, 0, 0x7F7F7F7F)
#define GLOAD_LDS(g, l) \
  __builtin_amdgcn_global_load_lds((const __attribute__((address_space(1))) void*)(g), \
                                   (__attribute__((address_space(3))) void*)(l), 16, 0, 0)

// ---------------------------------------------------------------------------
// Merged prep: blocks [0, CONV_BLK) do f32->fp8 conversion of ex_features
// (+pad zeroing), features, W (x8); blocks [CONV_BLK, CONV_BLK+EXCT_BLK)
// build excT fp8 + per-class counts (counts pre-zeroed by the memset).
// ---------------------------------------------------------------------------
__global__ void conv_all(const float* __restrict__ ex, const float* __restrict__ feat,
                         const float* __restrict__ Wg,
                         unsigned char* __restrict__ X8e, unsigned char* __restrict__ X8f,
                         unsigned char* __restrict__ W8,
                         const float* __restrict__ exc, unsigned char* __restrict__ excT8,
                         float* __restrict__ counts)
{
  __shared__ float lds[64][29];
  const int b = blockIdx.x;
  const int tid = threadIdx.x;
  if (b >= CONV_BLK) {
    // ---- excT + counts branch ----
    const int n0 = (b - CONV_BLK) * 64;
    for (int i = tid; i < 64 * L_SZ; i += 256) {
      const int n = i / L_SZ, l = i % L_SZ;
      lds[n][l] = (n0 + n < N_SZ) ? exc[(size_t)(n0 + n) * L_SZ + l] : 0.0f;
    }
    __syncthreads();
    if (tid < L_SZ) {
      float c = 0.f;
      for (int n = 0; n < 64; ++n) c += lds[n][tid];
      atomicAdd(&counts[tid], c);
    }
    for (int i = tid; i < 32 * 64; i += 256) {
      const int l = i >> 6, n = i & 63;
      excT8[(size_t)l * NP2 + n0 + n] = (l < L_SZ && lds[n][l] != 0.0f) ? 0x38 : 0x00;
    }
    return;
  }
  // ---- conversion branch ----
  const int T_EX = NP2 * 96, T_EXV = N_SZ * 96, T_F = B_SZ * 96;
  const int t = b * 256 + tid;
  const float* src; unsigned char* dst; float scale; int u;
  if (t < T_EX) {
    if (t >= T_EXV) { *(uint2*)(X8e + (size_t)t * 8) = make_uint2(0u, 0u); return; }
    src = ex; dst = X8e; scale = 1.0f; u = t;
  } else if (t < T_EX + T_F) {
    src = feat; dst = X8f; scale = 1.0f; u = t - T_EX;
  } else {
    src = Wg; dst = W8; scale = 8.0f; u = t - T_EX - T_F;
  }
  const float4 a0 = *(const float4*)(src + (size_t)u * 8);
  const float4 a1 = *(const float4*)(src + (size_t)u * 8 + 4);
  uint2 o;
  o.x = pk4_fp8(a0.x * scale, a0.y * scale, a0.z * scale, a0.w * scale);
  o.y = pk4_fp8(a1.x * scale, a1.y * scale, a1.z * scale, a1.w * scale);
  *(uint2*)(dst + (size_t)u * 8) = o;
}

// ---------------------------------------------------------------------------
// Projection GEMM, fp8 K=128 (round-10/13 proven, unchanged). Unnormalized
// fp8 Y + exact per-row ssq (f32 acc) via atomics. Co-XCD y-swizzle.
// ---------------------------------------------------------------------------
__global__ __launch_bounds__(256, 2)
void proj_gemm8(const unsigned char* __restrict__ Xf8,
                const unsigned char* __restrict__ Xe8,
                const unsigned char* __restrict__ W8,
                unsigned char* __restrict__ Yf8, unsigned char* __restrict__ Ye8,
                float* __restrict__ ssqF, float* __restrict__ ssqE)
{
  const int id = blockIdx.x;
  const int slot = id & 7, rest = id >> 3;
  const int x = rest % 6, yq = rest / 6;
  const int y = yq * 8 + slot;   // y in [0,400): 8 feature tiles + 392 ex tiles

  __shared__ __align__(16) unsigned char As8[2][128 * 128];
  __shared__ __align__(16) unsigned char Bs8[2][128 * 128];
  const int tid = threadIdx.x;
  const int w = tid >> 6, lane = tid & 63;
  const int wr = w >> 1, wc = w & 1;
  const int fr = lane & 15, fq = lane >> 4;
  const int srow = lane >> 3;
  const int schunk = (lane & 7) ^ srow;
  const int o0 = x * 128;

  const unsigned char* Xb; unsigned char* Y8; float* ssqG; int m0;
  if (y < 8) { Xb = Xf8; Y8 = Yf8; ssqG = ssqF; m0 = y * 128; }
  else       { Xb = Xe8; Y8 = Ye8; ssqG = ssqE; m0 = (y - 8) * 128; }

  auto stage = [&](int buf, int kk) {
#pragma unroll
    for (int i = 0; i < 4; ++i) {
      const int row = w * 32 + i * 8 + srow;
      GLOAD_LDS(Xb + (size_t)(m0 + row) * D_SZ + kk + schunk * 16,
                &As8[buf][(w * 32 + i * 8) * 128]);
      GLOAD_LDS(W8 + (size_t)(o0 + row) * D_SZ + kk + schunk * 16,
                &Bs8[buf][(w * 32 + i * 8) * 128]);
    }
  };

  f32x4 acc[4][4] = {};
  int cur = 0;
  stage(0, 0);

  for (int kk = 0; kk < D_SZ; kk += 128) {
    if (kk + 128 < D_SZ) {
      stage(cur ^ 1, kk + 128);
      asm volatile("s_waitcnt vmcnt(8)" ::: "memory");
    } else {
      asm volatile("s_waitcnt vmcnt(0)" ::: "memory");
    }
    __builtin_amdgcn_s_barrier();
    i32x8 af[4], bfv[4];
#pragma unroll
    for (int i = 0; i < 4; ++i) {
      {
        const int row = wr * 64 + i * 16 + fr;
        const int r7 = row & 7;
        const unsigned char* rb = &As8[cur][row * 128];
        af[i] = mk8(*(const uint4*)(rb + (((2 * fq + 0) ^ r7) << 4)),
                    *(const uint4*)(rb + (((2 * fq + 1) ^ r7) << 4)));
      }
      {
        const int row = wc * 64 + i * 16 + fr;
        const int r7 = row & 7;
        const unsigned char* rb = &Bs8[cur][row * 128];
        bfv[i] = mk8(*(const uint4*)(rb + (((2 * fq + 0) ^ r7) << 4)),
                     *(const uint4*)(rb + (((2 * fq + 1) ^ r7) << 4)));
      }
    }
#pragma unroll
    for (int mi = 0; mi < 4; ++mi)
#pragma unroll
      for (int ni = 0; ni < 4; ++ni)
        acc[mi][ni] = MFMA16(af[mi], bfv[ni], acc[mi][ni]);
    asm volatile("s_waitcnt lgkmcnt(0)" ::: "memory");
    __builtin_amdgcn_s_barrier();
    __builtin_amdgcn_sched_barrier(0);
    cur ^= 1;
  }

  float ssq[4][4] = {};
#pragma unroll
  for (int mi = 0; mi < 4; ++mi)
#pragma unroll
    for (int ni = 0; ni < 4; ++ni)
#pragma unroll
      for (int r = 0; r < 4; ++r) {
        const int row = m0 + wr * 64 + mi * 16 + fq * 4 + r;
        const int col = o0 + wc * 64 + ni * 16 + fr;
        const float v = acc[mi][ni][r];
        Y8[(size_t)row * D_SZ + col] = f2fp8(v);
        ssq[mi][r] += v * v;
      }
#pragma unroll
  for (int mi = 0; mi < 4; ++mi)
#pragma unroll
    for (int r = 0; r < 4; ++r) {
      float v = ssq[mi][r];
      v += __shfl_xor(v, 1); v += __shfl_xor(v, 2);
      v += __shfl_xor(v, 4); v += __shfl_xor(v, 8);
      if (fr == 0) atomicAdd(&ssqG[m0 + wr * 64 + mi * 16 + fq * 4 + r], v);
    }
}

// ---------------------------------------------------------------------------
// In-place fp8 row-normalize (r11/r13-proven). Single dispatch covers exfn8
// (rows 0..NP2-1, ssqE) AND fn8 (rows NP2.., ssqF) -- both contiguous in ws.
// ---------------------------------------------------------------------------
__global__ void normY(unsigned char* __restrict__ Y, const float* __restrict__ ssq, int n16)
{
  const int idx = blockIdx.x * 256 + threadIdx.x;
  if (idx >= n16) return;
  const int row = idx / 48;   // 48 uint4 per 768-B row
  const float rinv = 1.0f / fmaxf(sqrtf(ssq[row]), 1e-12f);
  uint4 v = *((const uint4*)Y + idx);
  unsigned o[4];
#pragma unroll
  for (int d = 0; d < 4; ++d) {
    const unsigned src = (&v.x)[d];
    unsigned r = 0;
#pragma unroll
    for (int i = 0; i < 4; ++i)
      r |= (unsigned)f2fp8(fp82f((src >> (8 * i)) & 0xFFu) * rinv) << (8 * i);
    o[d] = r;
  }
  *((uint4*)Y + idx) = make_uint4(o[0], o[1], o[2], o[3]);
}

// ---------------------------------------------------------------------------
// Fused s-GEMM (r13 pipeline, 4 tiles/block): swapped 32x32x64 MFMA,
// in-register cube+shfl-exchange phase-2, counted vmcnt(8) dbuf,
// pre-normalized inputs. Grid 784 blocks -> every CU holds 2 co-resident
// blocks (448-block version left 64 CUs with a single partnerless block
// setting the critical path). Slab = 4 tiles = 393 KB; 8 m-sharers/XCD L2.
// ---------------------------------------------------------------------------
__global__ __launch_bounds__(256, 1)
void echo_gemm8(const unsigned char* __restrict__ fn8,
                const unsigned char* __restrict__ exfn8,
                const unsigned char* __restrict__ excT8,
                float* __restrict__ echo)
{
  const int id = blockIdx.x;
  const int slot = id & 7, rest = id >> 3;
  const int m = rest & 7, xq = rest >> 3;
  const int x = xq * 8 + slot;
  if (x >= 98) return;
  const int m0 = m * 128;

  __shared__ __align__(16) unsigned char As8[2][128 * 128];  // exfn (n rows)
  __shared__ __align__(16) unsigned char Bs8[2][128 * 128];  // fn   (b rows)
  const int tid = threadIdx.x;
  const int w = tid >> 6, lane = tid & 63;
  const int nh = w >> 1, bh = w & 1;
  const int l31 = lane & 31, h = lane >> 5;
  const int srow = lane >> 3;
  const int schunk = (lane & 7) ^ srow;

  auto stage = [&](int buf, int n0s, int kk) {
#pragma unroll
    for (int i = 0; i < 4; ++i) {
      const int row = w * 32 + i * 8 + srow;
      GLOAD_LDS(exfn8 + (size_t)(n0s + row) * D_SZ + kk + schunk * 16,
                &As8[buf][(w * 32 + i * 8) * 128]);
      GLOAD_LDS(fn8 + (size_t)(m0 + row) * D_SZ + kk + schunk * 16,
                &Bs8[buf][(w * 32 + i * 8) * 128]);
    }
  };
  auto rdfrag = [&](const unsigned char* base, int row, int kh) -> i32x8 {
    const int r7 = row & 7;
    const unsigned char* rb = base + row * 128;
    return mk8(*(const uint4*)(rb + (((kh * 4 + h * 2 + 0) ^ r7) << 4)),
               *(const uint4*)(rb + (((kh * 4 + h * 2 + 1) ^ r7) << 4)));
  };

  f32x16 acc2[2] = {};
  int cur = 0;
  stage(0, x * 4 * 128, 0);

  for (int ti = 0; ti < 4; ++ti) {
    const int n0 = (x * 4 + ti) * 128;
    f32x16 acc[2][2] = {};   // [n-subtile t][b-subtile b2]
    for (int kk = 0; kk < D_SZ; kk += 128) {
      if (kk + 128 < D_SZ) {
        stage(cur ^ 1, n0, kk + 128);                    // 8 newer in flight
        asm volatile("s_waitcnt vmcnt(8)" ::: "memory"); // oldest 8 = cur done
      } else {
        asm volatile("s_waitcnt vmcnt(0)" ::: "memory");
      }
      __builtin_amdgcn_s_barrier();
#pragma unroll
      for (int kh = 0; kh < 2; ++kh) {
        i32x8 af0 = rdfrag(As8[cur], nh * 64 + l31, kh);
        i32x8 af1 = rdfrag(As8[cur], nh * 64 + 32 + l31, kh);
        i32x8 bf0 = rdfrag(Bs8[cur], bh * 64 + l31, kh);
        i32x8 bf1 = rdfrag(Bs8[cur], bh * 64 + 32 + l31, kh);
        __builtin_amdgcn_s_setprio(1);
        acc[0][0] = MFMA32(af0, bf0, acc[0][0]);
        acc[0][1] = MFMA32(af0, bf1, acc[0][1]);
        acc[1][0] = MFMA32(af1, bf0, acc[1][0]);
        acc[1][1] = MFMA32(af1, bf1, acc[1][1]);
        __builtin_amdgcn_s_setprio(0);
      }
      asm volatile("s_waitcnt lgkmcnt(0)" ::: "memory");
      __builtin_amdgcn_s_barrier();
      __builtin_amdgcn_sched_barrier(0);
      cur ^= 1;
    }
    // ---- epilogue: cube + in-reg exchange + phase-2 MFMA (no LDS) ----
#pragma unroll
    for (int b2 = 0; b2 < 2; ++b2) {
      unsigned frag[8];
#pragma unroll
      for (int q = 0; q < 4; ++q) {
        unsigned w0 = 0, w1 = 0;
#pragma unroll
        for (int i = 0; i < 4; ++i) {
          float v0 = acc[0][b2][4 * q + i] * 7.0f;
          float v1 = acc[1][b2][4 * q + i] * 7.0f;
          w0 |= (unsigned)f2fp8(v0 * v0 * v0) << (8 * i);
          w1 |= (unsigned)f2fp8(v1 * v1 * v1) << (8 * i);
        }
        const unsigned keep = h ? w1 : w0;   // my n-subtile t=h values
        const unsigned send = h ? w0 : w1;   // partner needs my t=1-h
        const unsigned recv = (unsigned)__shfl_xor((int)send, 32);
        frag[2 * q]     = h ? recv : keep;
        frag[2 * q + 1] = h ? keep : recv;
      }
      i32x8 pa;
#pragma unroll
      for (int k = 0; k < 8; ++k) pa[k] = (int)frag[k];
      const unsigned char* gp = excT8 + (size_t)l31 * NP2 + n0 + nh * 64 + h * 32;
      i32x8 pb = mk8(*(const uint4*)gp, *(const uint4*)(gp + 16));
      acc2[b2] = MFMA32(pa, pb, acc2[b2]);
    }
    if (ti + 1 < 4) stage(cur, n0 + 128, 0);  // next tile k0 after epilogue
  }
#pragma unroll
  for (int b2 = 0; b2 < 2; ++b2)
#pragma unroll
    for (int r = 0; r < 16; ++r) {
      const int b = m0 + bh * 64 + b2 * 32 + (r & 3) + 8 * (r >> 2) + 4 * h;
      if (l31 < L_SZ)
        atomicAdd(&echo[(size_t)b * L_SZ + l31], acc2[b2][r] * (1.0f / 343.0f));
    }
}

// ---------------------------------------------------------------------------
// Finalize: echo/counts -> neg_dists (vs real class_reps) -> BCE loss.
// ---------------------------------------------------------------------------
__global__ __launch_bounds__(1024)
void finalize(const float* __restrict__ echo, const float* __restrict__ counts,
              const float* __restrict__ labels, const float* __restrict__ creps,
              float* __restrict__ out)
{
  __shared__ float C[L_SZ * L_SZ];
  __shared__ float cnt[L_SZ];
  __shared__ float red[16];
  const int tid = threadIdx.x;
  if (tid < L_SZ * L_SZ) C[tid] = creps[tid];
  if (tid >= 896 && tid < 896 + L_SZ) cnt[tid - 896] = counts[tid - 896];
  __syncthreads();
  float e[L_SZ];
#pragma unroll
  for (int l = 0; l < L_SZ; ++l) e[l] = echo[tid * L_SZ + l] / cnt[l];
  float lsum = 0.f;
  for (int j = 0; j < L_SZ; ++j) {
    float d2 = 0.f;
#pragma unroll
    for (int l = 0; l < L_SZ; ++l) { const float df = e[l] - C[j * L_SZ + l]; d2 += df * df; }
    const float nd = -sqrtf(d2);
    out[1 + tid * L_SZ + j] = nd;
    const float y = labels[tid * L_SZ + j];
    const float sp = fmaxf(nd, 0.f) + log1pf(expf(-fabsf(nd)));
    lsum += sp - nd * y;
  }
#pragma unroll
  for (int o = 32; o; o >>= 1) lsum += __shfl_xor(lsum, o);
  if ((tid & 63) == 0) red[tid >> 6] = lsum;
  __syncthreads();
  if (tid < 16) {
    float v = red[tid];
#pragma unroll
    for (int o = 8; o; o >>= 1) v += __shfl_xor(v, o);
    if (tid == 0) out[0] = v * (1.0f / (B_SZ * L_SZ));
  }
}

extern "C" void kernel_launch(void* const* d_in, const int* in_sizes, int n_in,
                              void* d_out, int out_size, void* d_ws, size_t ws_size,
                              hipStream_t stream)
{
  (void)in_sizes; (void)n_in; (void)out_size;
  const float* features = (const float*)d_in[0];
  const float* labels   = (const float*)d_in[1];
  const float* W_g      = (const float*)d_in[2];
  const float* ex_feat  = (const float*)d_in[3];
  const float* ex_cls   = (const float*)d_in[4];
  const float* creps    = (const float*)d_in[5];
  float* out = (float*)d_out;

  const size_t OFF_EXFN8 = 0;                                   // NP2*768 = 38,535,168
  const size_t OFF_FN8   = OFF_EXFN8 + (size_t)NP2 * D_SZ;      // + 786,432 (contiguous after exfn8)
  const size_t OFF_EXCT8 = OFF_FN8 + (size_t)B_SZ * D_SZ;       // + 32*NP2 = 1,605,632
  const size_t OFF_X8E   = OFF_EXCT8 + (size_t)32 * NP2;        // + 38,535,168
  const size_t OFF_X8F   = OFF_X8E + (size_t)NP2 * D_SZ;        // + 786,432
  const size_t OFF_W8    = OFF_X8F + (size_t)B_SZ * D_SZ;       // + 589,824
  const size_t OFF_ECHO  = OFF_W8 + (size_t)D_SZ * D_SZ;        // + 114,688
  const size_t OFF_SSQE  = OFF_ECHO + (size_t)B_SZ * L_SZ * 4;  // + NP2*4 = 200,704
  const size_t OFF_SSQF  = OFF_SSQE + (size_t)NP2 * 4;          // + 4,096 (contiguous after ssqE)
  const size_t OFF_CNT   = OFF_SSQF + (size_t)B_SZ * 4;         // + 128
  const size_t NEED      = OFF_CNT + 128;                       // ~81.2 MB
  if (ws_size < NEED) return;

  char* ws = (char*)d_ws;
  unsigned char* exfn8 = (unsigned char*)(ws + OFF_EXFN8);
  unsigned char* fn8   = (unsigned char*)(ws + OFF_FN8);
  unsigned char* excT8 = (unsigned char*)(ws + OFF_EXCT8);
  unsigned char* X8e   = (unsigned char*)(ws + OFF_X8E);
  unsigned char* X8f   = (unsigned char*)(ws + OFF_X8F);
  unsigned char* W8    = (unsigned char*)(ws + OFF_W8);
  float* echo   = (float*)(ws + OFF_ECHO);
  float* ssqE   = (float*)(ws + OFF_SSQE);
  float* ssqF   = (float*)(ws + OFF_SSQF);
  float* counts = (float*)(ws + OFF_CNT);

  // zero echo + ssqE + ssqF + counts (contiguous span) -- before conv_all's
  // counts atomics
  hipMemsetAsync(ws + OFF_ECHO, 0, OFF_CNT + 128 - OFF_ECHO, stream);

  // merged conversion + excT build + counts (one dispatch)
  conv_all<<<dim3(CONV_BLK + EXCT_BLK), 256, 0, stream>>>(
      ex_feat, features, W_g, X8e, X8f, W8, ex_cls, excT8, counts);

  // proj: y in [0,400) -> 8 feature tiles + 392 ex tiles (covers NP2 rows)
  proj_gemm8<<<dim3(8 * 6 * 50), 256, 0, stream>>>(X8f, X8e, W8, fn8, exfn8, ssqF, ssqE);

  // single in-place L2-normalize over exfn8 THEN fn8 (contiguous rows)
  normY<<<dim3((NP2 + B_SZ) * 48 / 256), 256, 0, stream>>>(exfn8, ssqE, (NP2 + B_SZ) * 48);

  // grid: id = (x%8) + 8*(m + 8*(x/8)), x in [0,98), m in [0,8)
  echo_gemm8<<<dim3(8 * 8 * 13), 256, 0, stream>>>(fn8, exfn8, excT8, echo);
  finalize<<<dim3(1), 1024, 0, stream>>>(echo, counts, labels, creps, out);
}

// Round 17
// 236.329 us; speedup vs baseline: 1.0354x; 1.0354x over previous
//
#include <hip/hip_runtime.h>

#define D_SZ 768
#define N_SZ 50000
#define L_SZ 28
#define B_SZ 1024
#define NP2  50176   // 392*128 (padded N); 392 = 49*8 exactly

#define CONV_BLK 19488   // (NP2 + B_SZ + D_SZ) * 96 / 256
#define EXCT_BLK 784     // NP2 / 64

typedef float f32x4 __attribute__((ext_vector_type(4)));
typedef float f32x16 __attribute__((ext_vector_type(16)));
typedef int i32x8 __attribute__((ext_vector_type(8)));

// byte-order-proof single fp8 e4m3 convert (both packed bytes equal)
__device__ __forceinline__ unsigned char f2fp8(float a) {
  unsigned r;
  asm("v_cvt_pk_fp8_f32 %0, %1, %2" : "=v"(r) : "v"(a), "v"(a));
  return (unsigned char)(r & 0xFF);
}
__device__ __forceinline__ unsigned pk4_fp8(float a, float b, float c, float d) {
  unsigned lo, hi;
  asm("v_cvt_pk_fp8_f32 %0, %1, %2" : "=v"(lo) : "v"(a), "v"(b));
  asm("v_cvt_pk_fp8_f32 %0, %1, %2" : "=v"(hi) : "v"(c), "v"(d));
  return (lo & 0xFFFFu) | (hi << 16);
}
// exact fp8 e4m3 -> f32 (bit math; no NaN inputs occur here)
__device__ __forceinline__ float fp82f(unsigned b) {
  const int e = (b >> 3) & 15, mnt = b & 7;
  const float mag = ldexpf((float)(e ? mnt + 8 : mnt), (e ? e : 1) - 10);
  return (b & 0x80) ? -mag : mag;
}
__device__ __forceinline__ i32x8 mk8(uint4 lo, uint4 hi) {
  i32x8 r;
  r[0] = (int)lo.x; r[1] = (int)lo.y; r[2] = (int)lo.z; r[3] = (int)lo.w;
  r[4] = (int)hi.x; r[5] = (int)hi.y; r[6] = (int)hi.z; r[7] = (int)hi.w;
  return r;
}
#define MFMA16(a, b, c) \
  __builtin_amdgcn_mfma_scale_f32_16x16x128_f8f6f4((a), (b), (c), 0, 0, \
                                                   0, 0x7F7F7F7F, 0, 0x7F7F7F7F)
#define MFMA32(a, b, c) \
  __builtin_amdgcn_mfma_scale_f32_32x32x64_f8f6f4((a), (b), (c), 0, 0, \
                                                  0, 0x7F7F7F7F, 0, 0x7F7F7F7F)
#define GLOAD_LDS(g, l) \
  __builtin_amdgcn_global_load_lds((const __attribute__((address_space(1))) void*)(g), \
                                   (__attribute__((address_space(3))) void*)(l), 16, 0, 0)

// ---------------------------------------------------------------------------
// Merged prep (r16-proven): blocks [0, CONV_BLK) do f32->fp8 conversion of
// ex_features (+pad zeroing), features, W (x8); blocks [CONV_BLK, ...) build
// excT fp8 + per-class counts (counts pre-zeroed by the memset).
// ---------------------------------------------------------------------------
__global__ void conv_all(const float* __restrict__ ex, const float* __restrict__ feat,
                         const float* __restrict__ Wg,
                         unsigned char* __restrict__ X8e, unsigned char* __restrict__ X8f,
                         unsigned char* __restrict__ W8,
                         const float* __restrict__ exc, unsigned char* __restrict__ excT8,
                         float* __restrict__ counts)
{
  __shared__ float lds[64][29];
  const int b = blockIdx.x;
  const int tid = threadIdx.x;
  if (b >= CONV_BLK) {
    // ---- excT + counts branch ----
    const int n0 = (b - CONV_BLK) * 64;
    for (int i = tid; i < 64 * L_SZ; i += 256) {
      const int n = i / L_SZ, l = i % L_SZ;
      lds[n][l] = (n0 + n < N_SZ) ? exc[(size_t)(n0 + n) * L_SZ + l] : 0.0f;
    }
    __syncthreads();
    if (tid < L_SZ) {
      float c = 0.f;
      for (int n = 0; n < 64; ++n) c += lds[n][tid];
      atomicAdd(&counts[tid], c);
    }
    for (int i = tid; i < 32 * 64; i += 256) {
      const int l = i >> 6, n = i & 63;
      excT8[(size_t)l * NP2 + n0 + n] = (l < L_SZ && lds[n][l] != 0.0f) ? 0x38 : 0x00;
    }
    return;
  }
  // ---- conversion branch ----
  const int T_EX = NP2 * 96, T_EXV = N_SZ * 96, T_F = B_SZ * 96;
  const int t = b * 256 + tid;
  const float* src; unsigned char* dst; float scale; int u;
  if (t < T_EX) {
    if (t >= T_EXV) { *(uint2*)(X8e + (size_t)t * 8) = make_uint2(0u, 0u); return; }
    src = ex; dst = X8e; scale = 1.0f; u = t;
  } else if (t < T_EX + T_F) {
    src = feat; dst = X8f; scale = 1.0f; u = t - T_EX;
  } else {
    src = Wg; dst = W8; scale = 8.0f; u = t - T_EX - T_F;
  }
  const float4 a0 = *(const float4*)(src + (size_t)u * 8);
  const float4 a1 = *(const float4*)(src + (size_t)u * 8 + 4);
  uint2 o;
  o.x = pk4_fp8(a0.x * scale, a0.y * scale, a0.z * scale, a0.w * scale);
  o.y = pk4_fp8(a1.x * scale, a1.y * scale, a1.z * scale, a1.w * scale);
  *(uint2*)(dst + (size_t)u * 8) = o;
}

// ---------------------------------------------------------------------------
// Projection GEMM, fp8 K=128 (round-10/13 proven, unchanged). Unnormalized
// fp8 Y + exact per-row ssq (f32 acc) via atomics. Co-XCD y-swizzle.
// ---------------------------------------------------------------------------
__global__ __launch_bounds__(256, 2)
void proj_gemm8(const unsigned char* __restrict__ Xf8,
                const unsigned char* __restrict__ Xe8,
                const unsigned char* __restrict__ W8,
                unsigned char* __restrict__ Yf8, unsigned char* __restrict__ Ye8,
                float* __restrict__ ssqF, float* __restrict__ ssqE)
{
  const int id = blockIdx.x;
  const int slot = id & 7, rest = id >> 3;
  const int x = rest % 6, yq = rest / 6;
  const int y = yq * 8 + slot;   // y in [0,400): 8 feature tiles + 392 ex tiles

  __shared__ __align__(16) unsigned char As8[2][128 * 128];
  __shared__ __align__(16) unsigned char Bs8[2][128 * 128];
  const int tid = threadIdx.x;
  const int w = tid >> 6, lane = tid & 63;
  const int wr = w >> 1, wc = w & 1;
  const int fr = lane & 15, fq = lane >> 4;
  const int srow = lane >> 3;
  const int schunk = (lane & 7) ^ srow;
  const int o0 = x * 128;

  const unsigned char* Xb; unsigned char* Y8; float* ssqG; int m0;
  if (y < 8) { Xb = Xf8; Y8 = Yf8; ssqG = ssqF; m0 = y * 128; }
  else       { Xb = Xe8; Y8 = Ye8; ssqG = ssqE; m0 = (y - 8) * 128; }

  auto stage = [&](int buf, int kk) {
#pragma unroll
    for (int i = 0; i < 4; ++i) {
      const int row = w * 32 + i * 8 + srow;
      GLOAD_LDS(Xb + (size_t)(m0 + row) * D_SZ + kk + schunk * 16,
                &As8[buf][(w * 32 + i * 8) * 128]);
      GLOAD_LDS(W8 + (size_t)(o0 + row) * D_SZ + kk + schunk * 16,
                &Bs8[buf][(w * 32 + i * 8) * 128]);
    }
  };

  f32x4 acc[4][4] = {};
  int cur = 0;
  stage(0, 0);

  for (int kk = 0; kk < D_SZ; kk += 128) {
    if (kk + 128 < D_SZ) {
      stage(cur ^ 1, kk + 128);
      asm volatile("s_waitcnt vmcnt(8)" ::: "memory");
    } else {
      asm volatile("s_waitcnt vmcnt(0)" ::: "memory");
    }
    __builtin_amdgcn_s_barrier();
    i32x8 af[4], bfv[4];
#pragma unroll
    for (int i = 0; i < 4; ++i) {
      {
        const int row = wr * 64 + i * 16 + fr;
        const int r7 = row & 7;
        const unsigned char* rb = &As8[cur][row * 128];
        af[i] = mk8(*(const uint4*)(rb + (((2 * fq + 0) ^ r7) << 4)),
                    *(const uint4*)(rb + (((2 * fq + 1) ^ r7) << 4)));
      }
      {
        const int row = wc * 64 + i * 16 + fr;
        const int r7 = row & 7;
        const unsigned char* rb = &Bs8[cur][row * 128];
        bfv[i] = mk8(*(const uint4*)(rb + (((2 * fq + 0) ^ r7) << 4)),
                     *(const uint4*)(rb + (((2 * fq + 1) ^ r7) << 4)));
      }
    }
#pragma unroll
    for (int mi = 0; mi < 4; ++mi)
#pragma unroll
      for (int ni = 0; ni < 4; ++ni)
        acc[mi][ni] = MFMA16(af[mi], bfv[ni], acc[mi][ni]);
    asm volatile("s_waitcnt lgkmcnt(0)" ::: "memory");
    __builtin_amdgcn_s_barrier();
    __builtin_amdgcn_sched_barrier(0);
    cur ^= 1;
  }

  float ssq[4][4] = {};
#pragma unroll
  for (int mi = 0; mi < 4; ++mi)
#pragma unroll
    for (int ni = 0; ni < 4; ++ni)
#pragma unroll
      for (int r = 0; r < 4; ++r) {
        const int row = m0 + wr * 64 + mi * 16 + fq * 4 + r;
        const int col = o0 + wc * 64 + ni * 16 + fr;
        const float v = acc[mi][ni][r];
        Y8[(size_t)row * D_SZ + col] = f2fp8(v);
        ssq[mi][r] += v * v;
      }
#pragma unroll
  for (int mi = 0; mi < 4; ++mi)
#pragma unroll
    for (int r = 0; r < 4; ++r) {
      float v = ssq[mi][r];
      v += __shfl_xor(v, 1); v += __shfl_xor(v, 2);
      v += __shfl_xor(v, 4); v += __shfl_xor(v, 8);
      if (fr == 0) atomicAdd(&ssqG[m0 + wr * 64 + mi * 16 + fq * 4 + r], v);
    }
}

// ---------------------------------------------------------------------------
// In-place fp8 row-normalize (r11/r13-proven). Single dispatch covers exfn8
// (rows 0..NP2-1, ssqE) AND fn8 (rows NP2.., ssqF) -- both contiguous in ws.
// ---------------------------------------------------------------------------
__global__ void normY(unsigned char* __restrict__ Y, const float* __restrict__ ssq, int n16)
{
  const int idx = blockIdx.x * 256 + threadIdx.x;
  if (idx >= n16) return;
  const int row = idx / 48;   // 48 uint4 per 768-B row
  const float rinv = 1.0f / fmaxf(sqrtf(ssq[row]), 1e-12f);
  uint4 v = *((const uint4*)Y + idx);
  unsigned o[4];
#pragma unroll
  for (int d = 0; d < 4; ++d) {
    const unsigned src = (&v.x)[d];
    unsigned r = 0;
#pragma unroll
    for (int i = 0; i < 4; ++i)
      r |= (unsigned)f2fp8(fp82f((src >> (8 * i)) & 0xFFu) * rinv) << (8 * i);
    o[d] = r;
  }
  *((uint4*)Y + idx) = make_uint4(o[0], o[1], o[2], o[3]);
}

// ---------------------------------------------------------------------------
// Fused s-GEMM (round-13/15 EXACT, proven 87 us / VGPR 116 / absmax 0):
// swapped 32x32x64 MFMA, in-register cube+shfl-exchange phase-2, counted
// vmcnt(8) dbuf, pre-normalized inputs, 8 tiles/block (448 blocks -- the
// r16 784-block rebalance regressed +13 us: per-block prologue/drain and
// doubled atomics outweigh the straggler tail).
// ---------------------------------------------------------------------------
__global__ __launch_bounds__(256, 1)
void echo_gemm8(const unsigned char* __restrict__ fn8,
                const unsigned char* __restrict__ exfn8,
                const unsigned char* __restrict__ excT8,
                float* __restrict__ echo)
{
  const int id = blockIdx.x;
  const int slot = id & 7, rest = id >> 3;
  const int m = rest & 7, xq = rest >> 3;
  const int x = xq * 8 + slot;
  if (x >= 49) return;
  const int m0 = m * 128;

  __shared__ __align__(16) unsigned char As8[2][128 * 128];  // exfn (n rows)
  __shared__ __align__(16) unsigned char Bs8[2][128 * 128];  // fn   (b rows)
  const int tid = threadIdx.x;
  const int w = tid >> 6, lane = tid & 63;
  const int nh = w >> 1, bh = w & 1;
  const int l31 = lane & 31, h = lane >> 5;
  const int srow = lane >> 3;
  const int schunk = (lane & 7) ^ srow;

  auto stage = [&](int buf, int n0s, int kk) {
#pragma unroll
    for (int i = 0; i < 4; ++i) {
      const int row = w * 32 + i * 8 + srow;
      GLOAD_LDS(exfn8 + (size_t)(n0s + row) * D_SZ + kk + schunk * 16,
                &As8[buf][(w * 32 + i * 8) * 128]);
      GLOAD_LDS(fn8 + (size_t)(m0 + row) * D_SZ + kk + schunk * 16,
                &Bs8[buf][(w * 32 + i * 8) * 128]);
    }
  };
  auto rdfrag = [&](const unsigned char* base, int row, int kh) -> i32x8 {
    const int r7 = row & 7;
    const unsigned char* rb = base + row * 128;
    return mk8(*(const uint4*)(rb + (((kh * 4 + h * 2 + 0) ^ r7) << 4)),
               *(const uint4*)(rb + (((kh * 4 + h * 2 + 1) ^ r7) << 4)));
  };

  f32x16 acc2[2] = {};
  int cur = 0;
  stage(0, x * 8 * 128, 0);

  for (int ti = 0; ti < 8; ++ti) {
    const int n0 = (x * 8 + ti) * 128;
    f32x16 acc[2][2] = {};   // [n-subtile t][b-subtile b2]
    for (int kk = 0; kk < D_SZ; kk += 128) {
      if (kk + 128 < D_SZ) {
        stage(cur ^ 1, n0, kk + 128);                    // 8 newer in flight
        asm volatile("s_waitcnt vmcnt(8)" ::: "memory"); // oldest 8 = cur done
      } else {
        asm volatile("s_waitcnt vmcnt(0)" ::: "memory");
      }
      __builtin_amdgcn_s_barrier();
#pragma unroll
      for (int kh = 0; kh < 2; ++kh) {
        i32x8 af0 = rdfrag(As8[cur], nh * 64 + l31, kh);
        i32x8 af1 = rdfrag(As8[cur], nh * 64 + 32 + l31, kh);
        i32x8 bf0 = rdfrag(Bs8[cur], bh * 64 + l31, kh);
        i32x8 bf1 = rdfrag(Bs8[cur], bh * 64 + 32 + l31, kh);
        __builtin_amdgcn_s_setprio(1);
        acc[0][0] = MFMA32(af0, bf0, acc[0][0]);
        acc[0][1] = MFMA32(af0, bf1, acc[0][1]);
        acc[1][0] = MFMA32(af1, bf0, acc[1][0]);
        acc[1][1] = MFMA32(af1, bf1, acc[1][1]);
        __builtin_amdgcn_s_setprio(0);
      }
      asm volatile("s_waitcnt lgkmcnt(0)" ::: "memory");
      __builtin_amdgcn_s_barrier();
      __builtin_amdgcn_sched_barrier(0);
      cur ^= 1;
    }
    // ---- epilogue: cube + in-reg exchange + phase-2 MFMA (no LDS) ----
#pragma unroll
    for (int b2 = 0; b2 < 2; ++b2) {
      unsigned frag[8];
#pragma unroll
      for (int q = 0; q < 4; ++q) {
        unsigned w0 = 0, w1 = 0;
#pragma unroll
        for (int i = 0; i < 4; ++i) {
          float v0 = acc[0][b2][4 * q + i] * 7.0f;
          float v1 = acc[1][b2][4 * q + i] * 7.0f;
          w0 |= (unsigned)f2fp8(v0 * v0 * v0) << (8 * i);
          w1 |= (unsigned)f2fp8(v1 * v1 * v1) << (8 * i);
        }
        const unsigned keep = h ? w1 : w0;   // my n-subtile t=h values
        const unsigned send = h ? w0 : w1;   // partner needs my t=1-h
        const unsigned recv = (unsigned)__shfl_xor((int)send, 32);
        frag[2 * q]     = h ? recv : keep;
        frag[2 * q + 1] = h ? keep : recv;
      }
      i32x8 pa;
#pragma unroll
      for (int k = 0; k < 8; ++k) pa[k] = (int)frag[k];
      const unsigned char* gp = excT8 + (size_t)l31 * NP2 + n0 + nh * 64 + h * 32;
      i32x8 pb = mk8(*(const uint4*)gp, *(const uint4*)(gp + 16));
      acc2[b2] = MFMA32(pa, pb, acc2[b2]);
    }
    if (ti + 1 < 8) stage(cur, n0 + 128, 0);  // next tile k0 after epilogue
  }
#pragma unroll
  for (int b2 = 0; b2 < 2; ++b2)
#pragma unroll
    for (int r = 0; r < 16; ++r) {
      const int b = m0 + bh * 64 + b2 * 32 + (r & 3) + 8 * (r >> 2) + 4 * h;
      if (l31 < L_SZ)
        atomicAdd(&echo[(size_t)b * L_SZ + l31], acc2[b2][r] * (1.0f / 343.0f));
    }
}

// ---------------------------------------------------------------------------
// Finalize: echo/counts -> neg_dists (vs real class_reps) -> BCE loss.
// ---------------------------------------------------------------------------
__global__ __launch_bounds__(1024)
void finalize(const float* __restrict__ echo, const float* __restrict__ counts,
              const float* __restrict__ labels, const float* __restrict__ creps,
              float* __restrict__ out)
{
  __shared__ float C[L_SZ * L_SZ];
  __shared__ float cnt[L_SZ];
  __shared__ float red[16];
  const int tid = threadIdx.x;
  if (tid < L_SZ * L_SZ) C[tid] = creps[tid];
  if (tid >= 896 && tid < 896 + L_SZ) cnt[tid - 896] = counts[tid - 896];
  __syncthreads();
  float e[L_SZ];
#pragma unroll
  for (int l = 0; l < L_SZ; ++l) e[l] = echo[tid * L_SZ + l] / cnt[l];
  float lsum = 0.f;
  for (int j = 0; j < L_SZ; ++j) {
    float d2 = 0.f;
#pragma unroll
    for (int l = 0; l < L_SZ; ++l) { const float df = e[l] - C[j * L_SZ + l]; d2 += df * df; }
    const float nd = -sqrtf(d2);
    out[1 + tid * L_SZ + j] = nd;
    const float y = labels[tid * L_SZ + j];
    const float sp = fmaxf(nd, 0.f) + log1pf(expf(-fabsf(nd)));
    lsum += sp - nd * y;
  }
#pragma unroll
  for (int o = 32; o; o >>= 1) lsum += __shfl_xor(lsum, o);
  if ((tid & 63) == 0) red[tid >> 6] = lsum;
  __syncthreads();
  if (tid < 16) {
    float v = red[tid];
#pragma unroll
    for (int o = 8; o; o >>= 1) v += __shfl_xor(v, o);
    if (tid == 0) out[0] = v * (1.0f / (B_SZ * L_SZ));
  }
}

extern "C" void kernel_launch(void* const* d_in, const int* in_sizes, int n_in,
                              void* d_out, int out_size, void* d_ws, size_t ws_size,
                              hipStream_t stream)
{
  (void)in_sizes; (void)n_in; (void)out_size;
  const float* features = (const float*)d_in[0];
  const float* labels   = (const float*)d_in[1];
  const float* W_g      = (const float*)d_in[2];
  const float* ex_feat  = (const float*)d_in[3];
  const float* ex_cls   = (const float*)d_in[4];
  const float* creps    = (const float*)d_in[5];
  float* out = (float*)d_out;

  const size_t OFF_EXFN8 = 0;                                   // NP2*768 = 38,535,168
  const size_t OFF_FN8   = OFF_EXFN8 + (size_t)NP2 * D_SZ;      // + 786,432 (contiguous after exfn8)
  const size_t OFF_EXCT8 = OFF_FN8 + (size_t)B_SZ * D_SZ;       // + 32*NP2 = 1,605,632
  const size_t OFF_X8E   = OFF_EXCT8 + (size_t)32 * NP2;        // + 38,535,168
  const size_t OFF_X8F   = OFF_X8E + (size_t)NP2 * D_SZ;        // + 786,432
  const size_t OFF_W8    = OFF_X8F + (size_t)B_SZ * D_SZ;       // + 589,824
  const size_t OFF_ECHO  = OFF_W8 + (size_t)D_SZ * D_SZ;        // + 114,688
  const size_t OFF_SSQE  = OFF_ECHO + (size_t)B_SZ * L_SZ * 4;  // + NP2*4 = 200,704
  const size_t OFF_SSQF  = OFF_SSQE + (size_t)NP2 * 4;          // + 4,096 (contiguous after ssqE)
  const size_t OFF_CNT   = OFF_SSQF + (size_t)B_SZ * 4;         // + 128
  const size_t NEED      = OFF_CNT + 128;                       // ~81.2 MB
  if (ws_size < NEED) return;

  char* ws = (char*)d_ws;
  unsigned char* exfn8 = (unsigned char*)(ws + OFF_EXFN8);
  unsigned char* fn8   = (unsigned char*)(ws + OFF_FN8);
  unsigned char* excT8 = (unsigned char*)(ws + OFF_EXCT8);
  unsigned char* X8e   = (unsigned char*)(ws + OFF_X8E);
  unsigned char* X8f   = (unsigned char*)(ws + OFF_X8F);
  unsigned char* W8    = (unsigned char*)(ws + OFF_W8);
  float* echo   = (float*)(ws + OFF_ECHO);
  float* ssqE   = (float*)(ws + OFF_SSQE);
  float* ssqF   = (float*)(ws + OFF_SSQF);
  float* counts = (float*)(ws + OFF_CNT);

  // zero echo + ssqE + ssqF + counts (contiguous span) -- before conv_all's
  // counts atomics
  hipMemsetAsync(ws + OFF_ECHO, 0, OFF_CNT + 128 - OFF_ECHO, stream);

  // merged conversion + excT build + counts (one dispatch)
  conv_all<<<dim3(CONV_BLK + EXCT_BLK), 256, 0, stream>>>(
      ex_feat, features, W_g, X8e, X8f, W8, ex_cls, excT8, counts);

  // proj: y in [0,400) -> 8 feature tiles + 392 ex tiles (covers NP2 rows)
  proj_gemm8<<<dim3(8 * 6 * 50), 256, 0, stream>>>(X8f, X8e, W8, fn8, exfn8, ssqF, ssqE);

  // single in-place L2-normalize over exfn8 THEN fn8 (contiguous rows)
  normY<<<dim3((NP2 + B_SZ) * 48 / 256), 256, 0, stream>>>(exfn8, ssqE, (NP2 + B_SZ) * 48);

  // grid: id = (x%8) + 8*(m + 8*(x/8)), x in [0,49), m in [0,8)
  echo_gemm8<<<dim3(8 * 8 * 7), 256, 0, stream>>>(fn8, exfn8, excT8, echo);
  finalize<<<dim3(1), 1024, 0, stream>>>(echo, counts, labels, creps, out);
}

// Round 18
// 216.480 us; speedup vs baseline: 1.1303x; 1.0917x over previous
//
#include <hip/hip_runtime.h>

#define D_SZ 768
#define N_SZ 50000
#define L_SZ 28
#define B_SZ 1024
#define NP2  50176   // 392*128 (padded N); 392 = 49*8 exactly

#define CONV_BLK 19488   // (NP2 + B_SZ + D_SZ) * 96 / 256
#define EXCT_BLK 784     // NP2 / 64

typedef float f32x4 __attribute__((ext_vector_type(4)));
typedef float f32x16 __attribute__((ext_vector_type(16)));
typedef int i32x8 __attribute__((ext_vector_type(8)));

// byte-order-proof single fp8 e4m3 convert (both packed bytes equal)
__device__ __forceinline__ unsigned char f2fp8(float a) {
  unsigned r;
  asm("v_cvt_pk_fp8_f32 %0, %1, %2" : "=v"(r) : "v"(a), "v"(a));
  return (unsigned char)(r & 0xFF);
}
__device__ __forceinline__ unsigned pk4_fp8(float a, float b, float c, float d) {
  unsigned lo, hi;
  asm("v_cvt_pk_fp8_f32 %0, %1, %2" : "=v"(lo) : "v"(a), "v"(b));
  asm("v_cvt_pk_fp8_f32 %0, %1, %2" : "=v"(hi) : "v"(c), "v"(d));
  return (lo & 0xFFFFu) | (hi << 16);
}
__device__ __forceinline__ i32x8 mk8(uint4 lo, uint4 hi) {
  i32x8 r;
  r[0] = (int)lo.x; r[1] = (int)lo.y; r[2] = (int)lo.z; r[3] = (int)lo.w;
  r[4] = (int)hi.x; r[5] = (int)hi.y; r[6] = (int)hi.z; r[7] = (int)hi.w;
  return r;
}
#define MFMA16(a, b, c) \
  __builtin_amdgcn_mfma_scale_f32_16x16x128_f8f6f4((a), (b), (c), 0, 0, \
                                                   0, 0x7F7F7F7F, 0, 0x7F7F7F7F)
#define MFMA32(a, b, c) \
  __builtin_amdgcn_mfma_scale_f32_32x32x64_f8f6f4((a), (b), (c), 0, 0, \
                                                  0, 0x7F7F7F7F, 0, 0x7F7F7F7F)
#define GLOAD_LDS(g, l) \
  __builtin_amdgcn_global_load_lds((const __attribute__((address_space(1))) void*)(g), \
                                   (__attribute__((address_space(3))) void*)(l), 16, 0, 0)

// ---------------------------------------------------------------------------
// Merged prep (r16-proven): blocks [0, CONV_BLK) do f32->fp8 conversion of
// ex_features (+pad zeroing), features, W (x8); blocks [CONV_BLK, ...) build
// excT fp8 (binary 1.0/0.0) + per-class counts (counts pre-zeroed).
// ---------------------------------------------------------------------------
__global__ void conv_all(const float* __restrict__ ex, const float* __restrict__ feat,
                         const float* __restrict__ Wg,
                         unsigned char* __restrict__ X8e, unsigned char* __restrict__ X8f,
                         unsigned char* __restrict__ W8,
                         const float* __restrict__ exc, unsigned char* __restrict__ excT8,
                         float* __restrict__ counts)
{
  __shared__ float lds[64][29];
  const int b = blockIdx.x;
  const int tid = threadIdx.x;
  if (b >= CONV_BLK) {
    // ---- excT + counts branch ----
    const int n0 = (b - CONV_BLK) * 64;
    for (int i = tid; i < 64 * L_SZ; i += 256) {
      const int n = i / L_SZ, l = i % L_SZ;
      lds[n][l] = (n0 + n < N_SZ) ? exc[(size_t)(n0 + n) * L_SZ + l] : 0.0f;
    }
    __syncthreads();
    if (tid < L_SZ) {
      float c = 0.f;
      for (int n = 0; n < 64; ++n) c += lds[n][tid];
      atomicAdd(&counts[tid], c);
    }
    for (int i = tid; i < 32 * 64; i += 256) {
      const int l = i >> 6, n = i & 63;
      excT8[(size_t)l * NP2 + n0 + n] = (l < L_SZ && lds[n][l] != 0.0f) ? 0x38 : 0x00;
    }
    return;
  }
  // ---- conversion branch ----
  const int T_EX = NP2 * 96, T_EXV = N_SZ * 96, T_F = B_SZ * 96;
  const int t = b * 256 + tid;
  const float* src; unsigned char* dst; float scale; int u;
  if (t < T_EX) {
    if (t >= T_EXV) { *(uint2*)(X8e + (size_t)t * 8) = make_uint2(0u, 0u); return; }
    src = ex; dst = X8e; scale = 1.0f; u = t;
  } else if (t < T_EX + T_F) {
    src = feat; dst = X8f; scale = 1.0f; u = t - T_EX;
  } else {
    src = Wg; dst = W8; scale = 8.0f; u = t - T_EX - T_F;
  }
  const float4 a0 = *(const float4*)(src + (size_t)u * 8);
  const float4 a1 = *(const float4*)(src + (size_t)u * 8 + 4);
  uint2 o;
  o.x = pk4_fp8(a0.x * scale, a0.y * scale, a0.z * scale, a0.w * scale);
  o.y = pk4_fp8(a1.x * scale, a1.y * scale, a1.z * scale, a1.w * scale);
  *(uint2*)(dst + (size_t)u * 8) = o;
}

// ---------------------------------------------------------------------------
// Projection GEMM, fp8 K=128 (round-10/13 proven, unchanged). Unnormalized
// fp8 Y + exact per-row ssq (f32 acc) via atomics. Co-XCD y-swizzle.
// ---------------------------------------------------------------------------
__global__ __launch_bounds__(256, 2)
void proj_gemm8(const unsigned char* __restrict__ Xf8,
                const unsigned char* __restrict__ Xe8,
                const unsigned char* __restrict__ W8,
                unsigned char* __restrict__ Yf8, unsigned char* __restrict__ Ye8,
                float* __restrict__ ssqF, float* __restrict__ ssqE)
{
  const int id = blockIdx.x;
  const int slot = id & 7, rest = id >> 3;
  const int x = rest % 6, yq = rest / 6;
  const int y = yq * 8 + slot;   // y in [0,400): 8 feature tiles + 392 ex tiles

  __shared__ __align__(16) unsigned char As8[2][128 * 128];
  __shared__ __align__(16) unsigned char Bs8[2][128 * 128];
  const int tid = threadIdx.x;
  const int w = tid >> 6, lane = tid & 63;
  const int wr = w >> 1, wc = w & 1;
  const int fr = lane & 15, fq = lane >> 4;
  const int srow = lane >> 3;
  const int schunk = (lane & 7) ^ srow;
  const int o0 = x * 128;

  const unsigned char* Xb; unsigned char* Y8; float* ssqG; int m0;
  if (y < 8) { Xb = Xf8; Y8 = Yf8; ssqG = ssqF; m0 = y * 128; }
  else       { Xb = Xe8; Y8 = Ye8; ssqG = ssqE; m0 = (y - 8) * 128; }

  auto stage = [&](int buf, int kk) {
#pragma unroll
    for (int i = 0; i < 4; ++i) {
      const int row = w * 32 + i * 8 + srow;
      GLOAD_LDS(Xb + (size_t)(m0 + row) * D_SZ + kk + schunk * 16,
                &As8[buf][(w * 32 + i * 8) * 128]);
      GLOAD_LDS(W8 + (size_t)(o0 + row) * D_SZ + kk + schunk * 16,
                &Bs8[buf][(w * 32 + i * 8) * 128]);
    }
  };

  f32x4 acc[4][4] = {};
  int cur = 0;
  stage(0, 0);

  for (int kk = 0; kk < D_SZ; kk += 128) {
    if (kk + 128 < D_SZ) {
      stage(cur ^ 1, kk + 128);
      asm volatile("s_waitcnt vmcnt(8)" ::: "memory");
    } else {
      asm volatile("s_waitcnt vmcnt(0)" ::: "memory");
    }
    __builtin_amdgcn_s_barrier();
    i32x8 af[4], bfv[4];
#pragma unroll
    for (int i = 0; i < 4; ++i) {
      {
        const int row = wr * 64 + i * 16 + fr;
        const int r7 = row & 7;
        const unsigned char* rb = &As8[cur][row * 128];
        af[i] = mk8(*(const uint4*)(rb + (((2 * fq + 0) ^ r7) << 4)),
                    *(const uint4*)(rb + (((2 * fq + 1) ^ r7) << 4)));
      }
      {
        const int row = wc * 64 + i * 16 + fr;
        const int r7 = row & 7;
        const unsigned char* rb = &Bs8[cur][row * 128];
        bfv[i] = mk8(*(const uint4*)(rb + (((2 * fq + 0) ^ r7) << 4)),
                     *(const uint4*)(rb + (((2 * fq + 1) ^ r7) << 4)));
      }
    }
#pragma unroll
    for (int mi = 0; mi < 4; ++mi)
#pragma unroll
      for (int ni = 0; ni < 4; ++ni)
        acc[mi][ni] = MFMA16(af[mi], bfv[ni], acc[mi][ni]);
    asm volatile("s_waitcnt lgkmcnt(0)" ::: "memory");
    __builtin_amdgcn_s_barrier();
    __builtin_amdgcn_sched_barrier(0);
    cur ^= 1;
  }

  float ssq[4][4] = {};
#pragma unroll
  for (int mi = 0; mi < 4; ++mi)
#pragma unroll
    for (int ni = 0; ni < 4; ++ni)
#pragma unroll
      for (int r = 0; r < 4; ++r) {
        const int row = m0 + wr * 64 + mi * 16 + fq * 4 + r;
        const int col = o0 + wc * 64 + ni * 16 + fr;
        const float v = acc[mi][ni][r];
        Y8[(size_t)row * D_SZ + col] = f2fp8(v);
        ssq[mi][r] += v * v;
      }
#pragma unroll
  for (int mi = 0; mi < 4; ++mi)
#pragma unroll
    for (int r = 0; r < 4; ++r) {
      float v = ssq[mi][r];
      v += __shfl_xor(v, 1); v += __shfl_xor(v, 2);
      v += __shfl_xor(v, 4); v += __shfl_xor(v, 8);
      if (fr == 0) atomicAdd(&ssqG[m0 + wr * 64 + mi * 16 + fq * 4 + r], v);
    }
}

// ---------------------------------------------------------------------------
// Fold rne_n^3 into excT: excT'[l][n] = exc[n][l] ? (128/||y_n||)^3 : 0.
// Replaces the 79 MB normY pass with a 3.2 MB one. Coalesced per-l rows.
// ---------------------------------------------------------------------------
__global__ void excT_scale(unsigned char* __restrict__ excT8, const float* __restrict__ ssqE)
{
  const int n = blockIdx.x * 256 + threadIdx.x;
  if (n >= NP2) return;
  const float nrm = fmaxf(sqrtf(ssqE[n]), 1e-12f);
  const float iv = 128.0f / nrm;
  const unsigned char g8 = f2fp8(iv * iv * iv);
#pragma unroll
  for (int l = 0; l < L_SZ; ++l) {
    unsigned char* p = excT8 + (size_t)l * NP2 + n;
    *p = *p ? g8 : (unsigned char)0;
  }
}

// ---------------------------------------------------------------------------
// Fused s-GEMM (r13/r17 structure, proven 87 us / VGPR 116): swapped 32x32x64
// MFMA, in-register cube+shfl-exchange phase-2, counted vmcnt(8) dbuf,
// 8 tiles/block. Inputs now UNNORMALIZED: dot = y_b . y_n; epilogue cubes
// (dot/1024)^3; rne^3 is pre-folded into excT8, rf^3 applied in finalize.
// ---------------------------------------------------------------------------
__global__ __launch_bounds__(256, 1)
void echo_gemm8(const unsigned char* __restrict__ fn8,
                const unsigned char* __restrict__ exfn8,
                const unsigned char* __restrict__ excT8,
                float* __restrict__ echo)
{
  const int id = blockIdx.x;
  const int slot = id & 7, rest = id >> 3;
  const int m = rest & 7, xq = rest >> 3;
  const int x = xq * 8 + slot;
  if (x >= 49) return;
  const int m0 = m * 128;

  __shared__ __align__(16) unsigned char As8[2][128 * 128];  // exfn (n rows)
  __shared__ __align__(16) unsigned char Bs8[2][128 * 128];  // fn   (b rows)
  const int tid = threadIdx.x;
  const int w = tid >> 6, lane = tid & 63;
  const int nh = w >> 1, bh = w & 1;
  const int l31 = lane & 31, h = lane >> 5;
  const int srow = lane >> 3;
  const int schunk = (lane & 7) ^ srow;

  auto stage = [&](int buf, int n0s, int kk) {
#pragma unroll
    for (int i = 0; i < 4; ++i) {
      const int row = w * 32 + i * 8 + srow;
      GLOAD_LDS(exfn8 + (size_t)(n0s + row) * D_SZ + kk + schunk * 16,
                &As8[buf][(w * 32 + i * 8) * 128]);
      GLOAD_LDS(fn8 + (size_t)(m0 + row) * D_SZ + kk + schunk * 16,
                &Bs8[buf][(w * 32 + i * 8) * 128]);
    }
  };
  auto rdfrag = [&](const unsigned char* base, int row, int kh) -> i32x8 {
    const int r7 = row & 7;
    const unsigned char* rb = base + row * 128;
    return mk8(*(const uint4*)(rb + (((kh * 4 + h * 2 + 0) ^ r7) << 4)),
               *(const uint4*)(rb + (((kh * 4 + h * 2 + 1) ^ r7) << 4)));
  };

  f32x16 acc2[2] = {};
  int cur = 0;
  stage(0, x * 8 * 128, 0);

  for (int ti = 0; ti < 8; ++ti) {
    const int n0 = (x * 8 + ti) * 128;
    f32x16 acc[2][2] = {};   // [n-subtile t][b-subtile b2]
    for (int kk = 0; kk < D_SZ; kk += 128) {
      if (kk + 128 < D_SZ) {
        stage(cur ^ 1, n0, kk + 128);                    // 8 newer in flight
        asm volatile("s_waitcnt vmcnt(8)" ::: "memory"); // oldest 8 = cur done
      } else {
        asm volatile("s_waitcnt vmcnt(0)" ::: "memory");
      }
      __builtin_amdgcn_s_barrier();
#pragma unroll
      for (int kh = 0; kh < 2; ++kh) {
        i32x8 af0 = rdfrag(As8[cur], nh * 64 + l31, kh);
        i32x8 af1 = rdfrag(As8[cur], nh * 64 + 32 + l31, kh);
        i32x8 bf0 = rdfrag(Bs8[cur], bh * 64 + l31, kh);
        i32x8 bf1 = rdfrag(Bs8[cur], bh * 64 + 32 + l31, kh);
        __builtin_amdgcn_s_setprio(1);
        acc[0][0] = MFMA32(af0, bf0, acc[0][0]);
        acc[0][1] = MFMA32(af0, bf1, acc[0][1]);
        acc[1][0] = MFMA32(af1, bf0, acc[1][0]);
        acc[1][1] = MFMA32(af1, bf1, acc[1][1]);
        __builtin_amdgcn_s_setprio(0);
      }
      asm volatile("s_waitcnt lgkmcnt(0)" ::: "memory");
      __builtin_amdgcn_s_barrier();
      __builtin_amdgcn_sched_barrier(0);
      cur ^= 1;
    }
    // ---- epilogue: cube (x 1/1024) + in-reg exchange + phase-2 MFMA ----
#pragma unroll
    for (int b2 = 0; b2 < 2; ++b2) {
      unsigned frag[8];
#pragma unroll
      for (int q = 0; q < 4; ++q) {
        unsigned w0 = 0, w1 = 0;
#pragma unroll
        for (int i = 0; i < 4; ++i) {
          float v0 = acc[0][b2][4 * q + i] * (1.0f / 1024.0f);
          float v1 = acc[1][b2][4 * q + i] * (1.0f / 1024.0f);
          w0 |= (unsigned)f2fp8(v0 * v0 * v0) << (8 * i);
          w1 |= (unsigned)f2fp8(v1 * v1 * v1) << (8 * i);
        }
        const unsigned keep = h ? w1 : w0;   // my n-subtile t=h values
        const unsigned send = h ? w0 : w1;   // partner needs my t=1-h
        const unsigned recv = (unsigned)__shfl_xor((int)send, 32);
        frag[2 * q]     = h ? recv : keep;
        frag[2 * q + 1] = h ? keep : recv;
      }
      i32x8 pa;
#pragma unroll
      for (int k = 0; k < 8; ++k) pa[k] = (int)frag[k];
      const unsigned char* gp = excT8 + (size_t)l31 * NP2 + n0 + nh * 64 + h * 32;
      i32x8 pb = mk8(*(const uint4*)gp, *(const uint4*)(gp + 16));
      acc2[b2] = MFMA32(pa, pb, acc2[b2]);
    }
    if (ti + 1 < 8) stage(cur, n0 + 128, 0);  // next tile k0 after epilogue
  }
#pragma unroll
  for (int b2 = 0; b2 < 2; ++b2)
#pragma unroll
    for (int r = 0; r < 16; ++r) {
      const int b = m0 + bh * 64 + b2 * 32 + (r & 3) + 8 * (r >> 2) + 4 * h;
      if (l31 < L_SZ)
        atomicAdd(&echo[(size_t)b * L_SZ + l31], acc2[b2][r]);
    }
}

// ---------------------------------------------------------------------------
// Finalize: echo * rf_b^3-scale / counts -> neg_dists -> BCE loss.
// scale_b = 512 / ||y_b||^3  (512 = (1024/128)^3 undoes alpha and c).
// ---------------------------------------------------------------------------
__global__ __launch_bounds__(1024)
void finalize(const float* __restrict__ echo, const float* __restrict__ counts,
              const float* __restrict__ ssqF,
              const float* __restrict__ labels, const float* __restrict__ creps,
              float* __restrict__ out)
{
  __shared__ float C[L_SZ * L_SZ];
  __shared__ float cnt[L_SZ];
  __shared__ float red[16];
  const int tid = threadIdx.x;
  if (tid < L_SZ * L_SZ) C[tid] = creps[tid];
  if (tid >= 896 && tid < 896 + L_SZ) cnt[tid - 896] = counts[tid - 896];
  __syncthreads();
  const float nb = fmaxf(sqrtf(ssqF[tid]), 1e-12f);
  const float sb = 512.0f / (nb * nb * nb);
  float e[L_SZ];
#pragma unroll
  for (int l = 0; l < L_SZ; ++l) e[l] = echo[tid * L_SZ + l] * sb / cnt[l];
  float lsum = 0.f;
  for (int j = 0; j < L_SZ; ++j) {
    float d2 = 0.f;
#pragma unroll
    for (int l = 0; l < L_SZ; ++l) { const float df = e[l] - C[j * L_SZ + l]; d2 += df * df; }
    const float nd = -sqrtf(d2);
    out[1 + tid * L_SZ + j] = nd;
    const float y = labels[tid * L_SZ + j];
    const float sp = fmaxf(nd, 0.f) + log1pf(expf(-fabsf(nd)));
    lsum += sp - nd * y;
  }
#pragma unroll
  for (int o = 32; o; o >>= 1) lsum += __shfl_xor(lsum, o);
  if ((tid & 63) == 0) red[tid >> 6] = lsum;
  __syncthreads();
  if (tid < 16) {
    float v = red[tid];
#pragma unroll
    for (int o = 8; o; o >>= 1) v += __shfl_xor(v, o);
    if (tid == 0) out[0] = v * (1.0f / (B_SZ * L_SZ));
  }
}

extern "C" void kernel_launch(void* const* d_in, const int* in_sizes, int n_in,
                              void* d_out, int out_size, void* d_ws, size_t ws_size,
                              hipStream_t stream)
{
  (void)in_sizes; (void)n_in; (void)out_size;
  const float* features = (const float*)d_in[0];
  const float* labels   = (const float*)d_in[1];
  const float* W_g      = (const float*)d_in[2];
  const float* ex_feat  = (const float*)d_in[3];
  const float* ex_cls   = (const float*)d_in[4];
  const float* creps    = (const float*)d_in[5];
  float* out = (float*)d_out;

  const size_t OFF_EXFN8 = 0;                                   // NP2*768 = 38,535,168
  const size_t OFF_FN8   = OFF_EXFN8 + (size_t)NP2 * D_SZ;      // + 786,432
  const size_t OFF_EXCT8 = OFF_FN8 + (size_t)B_SZ * D_SZ;       // + 32*NP2 = 1,605,632
  const size_t OFF_X8E   = OFF_EXCT8 + (size_t)32 * NP2;        // + 38,535,168
  const size_t OFF_X8F   = OFF_X8E + (size_t)NP2 * D_SZ;        // + 786,432
  const size_t OFF_W8    = OFF_X8F + (size_t)B_SZ * D_SZ;       // + 589,824
  const size_t OFF_ECHO  = OFF_W8 + (size_t)D_SZ * D_SZ;        // + 114,688
  const size_t OFF_SSQE  = OFF_ECHO + (size_t)B_SZ * L_SZ * 4;  // + NP2*4 = 200,704
  const size_t OFF_SSQF  = OFF_SSQE + (size_t)NP2 * 4;          // + 4,096
  const size_t OFF_CNT   = OFF_SSQF + (size_t)B_SZ * 4;         // + 128
  const size_t NEED      = OFF_CNT + 128;                       // ~81.2 MB
  if (ws_size < NEED) return;

  char* ws = (char*)d_ws;
  unsigned char* exfn8 = (unsigned char*)(ws + OFF_EXFN8);
  unsigned char* fn8   = (unsigned char*)(ws + OFF_FN8);
  unsigned char* excT8 = (unsigned char*)(ws + OFF_EXCT8);
  unsigned char* X8e   = (unsigned char*)(ws + OFF_X8E);
  unsigned char* X8f   = (unsigned char*)(ws + OFF_X8F);
  unsigned char* W8    = (unsigned char*)(ws + OFF_W8);
  float* echo   = (float*)(ws + OFF_ECHO);
  float* ssqE   = (float*)(ws + OFF_SSQE);
  float* ssqF   = (float*)(ws + OFF_SSQF);
  float* counts = (float*)(ws + OFF_CNT);

  // zero echo + ssqE + ssqF + counts (contiguous span) -- before conv_all's
  // counts atomics
  hipMemsetAsync(ws + OFF_ECHO, 0, OFF_CNT + 128 - OFF_ECHO, stream);

  // merged conversion + excT build + counts (one dispatch)
  conv_all<<<dim3(CONV_BLK + EXCT_BLK), 256, 0, stream>>>(
      ex_feat, features, W_g, X8e, X8f, W8, ex_cls, excT8, counts);

  // proj: y in [0,400) -> 8 feature tiles + 392 ex tiles (covers NP2 rows)
  proj_gemm8<<<dim3(8 * 6 * 50), 256, 0, stream>>>(X8f, X8e, W8, fn8, exfn8, ssqF, ssqE);

  // fold rne^3 into excT (replaces the 79 MB normY pass)
  excT_scale<<<dim3(NP2 / 256), 256, 0, stream>>>(excT8, ssqE);

  // grid: id = (x%8) + 8*(m + 8*(x/8)), x in [0,49), m in [0,8)
  echo_gemm8<<<dim3(8 * 8 * 7), 256, 0, stream>>>(fn8, exfn8, excT8, echo);
  finalize<<<dim3(1), 1024, 0, stream>>>(echo, counts, ssqF, labels, creps, out);
}

// Round 19
// 211.431 us; speedup vs baseline: 1.1573x; 1.0239x over previous
//
#include <hip/hip_runtime.h>

#define D_SZ 768
#define N_SZ 50000
#define L_SZ 28
#define B_SZ 1024
#define NP2  50176   // 392*128 (padded N); 392 = 49*8 exactly

#define CONV_BLK 19488   // (NP2 + B_SZ + D_SZ) * 96 / 256
#define EXCT_BLK 784     // NP2 / 64
#define ZERO_BLK 78      // 78 * 256 * 16 B = 319,488 B = echo+ssqE+ssqF span

typedef float f32x4 __attribute__((ext_vector_type(4)));
typedef float f32x16 __attribute__((ext_vector_type(16)));
typedef int i32x8 __attribute__((ext_vector_type(8)));

// byte-order-proof single fp8 e4m3 convert (both packed bytes equal)
__device__ __forceinline__ unsigned char f2fp8(float a) {
  unsigned r;
  asm("v_cvt_pk_fp8_f32 %0, %1, %2" : "=v"(r) : "v"(a), "v"(a));
  return (unsigned char)(r & 0xFF);
}
__device__ __forceinline__ unsigned pk4_fp8(float a, float b, float c, float d) {
  unsigned lo, hi;
  asm("v_cvt_pk_fp8_f32 %0, %1, %2" : "=v"(lo) : "v"(a), "v"(b));
  asm("v_cvt_pk_fp8_f32 %0, %1, %2" : "=v"(hi) : "v"(c), "v"(d));
  return (lo & 0xFFFFu) | (hi << 16);
}
__device__ __forceinline__ i32x8 mk8(uint4 lo, uint4 hi) {
  i32x8 r;
  r[0] = (int)lo.x; r[1] = (int)lo.y; r[2] = (int)lo.z; r[3] = (int)lo.w;
  r[4] = (int)hi.x; r[5] = (int)hi.y; r[6] = (int)hi.z; r[7] = (int)hi.w;
  return r;
}
#define MFMA16(a, b, c) \
  __builtin_amdgcn_mfma_scale_f32_16x16x128_f8f6f4((a), (b), (c), 0, 0, \
                                                   0, 0x7F7F7F7F, 0, 0x7F7F7F7F)
#define MFMA32(a, b, c) \
  __builtin_amdgcn_mfma_scale_f32_32x32x64_f8f6f4((a), (b), (c), 0, 0, \
                                                  0, 0x7F7F7F7F, 0, 0x7F7F7F7F)
#define GLOAD_LDS(g, l) \
  __builtin_amdgcn_global_load_lds((const __attribute__((address_space(1))) void*)(g), \
                                   (__attribute__((address_space(3))) void*)(l), 16, 0, 0)

// ---------------------------------------------------------------------------
// Merged prep: [0, CONV_BLK) f32->fp8 conversion (ex +pad-zero, feat, W x8);
// [CONV_BLK, +EXCT_BLK) excT fp8 + per-block count partials (race-free,
// no pre-zero needed); [CONV_BLK+EXCT_BLK, +ZERO_BLK) zero echo/ssqE/ssqF
// (consumed only by LATER kernels' atomics -> safe in-kernel).
// ---------------------------------------------------------------------------
__global__ void conv_all(const float* __restrict__ ex, const float* __restrict__ feat,
                         const float* __restrict__ Wg,
                         unsigned char* __restrict__ X8e, unsigned char* __restrict__ X8f,
                         unsigned char* __restrict__ W8,
                         const float* __restrict__ exc, unsigned char* __restrict__ excT8,
                         float* __restrict__ cpart, uint4* __restrict__ zspan)
{
  __shared__ float lds[64][29];
  const int b = blockIdx.x;
  const int tid = threadIdx.x;
  if (b >= CONV_BLK + EXCT_BLK) {
    // ---- zero branch: echo + ssqE + ssqF (319,488 B) ----
    zspan[(b - CONV_BLK - EXCT_BLK) * 256 + tid] = make_uint4(0u, 0u, 0u, 0u);
    return;
  }
  if (b >= CONV_BLK) {
    // ---- excT + count-partials branch ----
    const int j = b - CONV_BLK;
    const int n0 = j * 64;
    for (int i = tid; i < 64 * L_SZ; i += 256) {
      const int n = i / L_SZ, l = i % L_SZ;
      lds[n][l] = (n0 + n < N_SZ) ? exc[(size_t)(n0 + n) * L_SZ + l] : 0.0f;
    }
    __syncthreads();
    if (tid < L_SZ) {
      float c = 0.f;
      for (int n = 0; n < 64; ++n) c += lds[n][tid];
      cpart[(size_t)j * L_SZ + tid] = c;   // unconditional write, no init needed
    }
    for (int i = tid; i < 32 * 64; i += 256) {
      const int l = i >> 6, n = i & 63;
      excT8[(size_t)l * NP2 + n0 + n] = (l < L_SZ && lds[n][l] != 0.0f) ? 0x38 : 0x00;
    }
    return;
  }
  // ---- conversion branch ----
  const int T_EX = NP2 * 96, T_EXV = N_SZ * 96, T_F = B_SZ * 96;
  const int t = b * 256 + tid;
  const float* src; unsigned char* dst; float scale; int u;
  if (t < T_EX) {
    if (t >= T_EXV) { *(uint2*)(X8e + (size_t)t * 8) = make_uint2(0u, 0u); return; }
    src = ex; dst = X8e; scale = 1.0f; u = t;
  } else if (t < T_EX + T_F) {
    src = feat; dst = X8f; scale = 1.0f; u = t - T_EX;
  } else {
    src = Wg; dst = W8; scale = 8.0f; u = t - T_EX - T_F;
  }
  const float4 a0 = *(const float4*)(src + (size_t)u * 8);
  const float4 a1 = *(const float4*)(src + (size_t)u * 8 + 4);
  uint2 o;
  o.x = pk4_fp8(a0.x * scale, a0.y * scale, a0.z * scale, a0.w * scale);
  o.y = pk4_fp8(a1.x * scale, a1.y * scale, a1.z * scale, a1.w * scale);
  *(uint2*)(dst + (size_t)u * 8) = o;
}

// ---------------------------------------------------------------------------
// Projection GEMM, fp8 K=128 (round-10/13 proven, unchanged). Unnormalized
// fp8 Y + exact per-row ssq (f32 acc) via atomics. Co-XCD y-swizzle.
// ---------------------------------------------------------------------------
__global__ __launch_bounds__(256, 2)
void proj_gemm8(const unsigned char* __restrict__ Xf8,
                const unsigned char* __restrict__ Xe8,
                const unsigned char* __restrict__ W8,
                unsigned char* __restrict__ Yf8, unsigned char* __restrict__ Ye8,
                float* __restrict__ ssqF, float* __restrict__ ssqE)
{
  const int id = blockIdx.x;
  const int slot = id & 7, rest = id >> 3;
  const int x = rest % 6, yq = rest / 6;
  const int y = yq * 8 + slot;   // y in [0,400): 8 feature tiles + 392 ex tiles

  __shared__ __align__(16) unsigned char As8[2][128 * 128];
  __shared__ __align__(16) unsigned char Bs8[2][128 * 128];
  const int tid = threadIdx.x;
  const int w = tid >> 6, lane = tid & 63;
  const int wr = w >> 1, wc = w & 1;
  const int fr = lane & 15, fq = lane >> 4;
  const int srow = lane >> 3;
  const int schunk = (lane & 7) ^ srow;
  const int o0 = x * 128;

  const unsigned char* Xb; unsigned char* Y8; float* ssqG; int m0;
  if (y < 8) { Xb = Xf8; Y8 = Yf8; ssqG = ssqF; m0 = y * 128; }
  else       { Xb = Xe8; Y8 = Ye8; ssqG = ssqE; m0 = (y - 8) * 128; }

  auto stage = [&](int buf, int kk) {
#pragma unroll
    for (int i = 0; i < 4; ++i) {
      const int row = w * 32 + i * 8 + srow;
      GLOAD_LDS(Xb + (size_t)(m0 + row) * D_SZ + kk + schunk * 16,
                &As8[buf][(w * 32 + i * 8) * 128]);
      GLOAD_LDS(W8 + (size_t)(o0 + row) * D_SZ + kk + schunk * 16,
                &Bs8[buf][(w * 32 + i * 8) * 128]);
    }
  };

  f32x4 acc[4][4] = {};
  int cur = 0;
  stage(0, 0);

  for (int kk = 0; kk < D_SZ; kk += 128) {
    if (kk + 128 < D_SZ) {
      stage(cur ^ 1, kk + 128);
      asm volatile("s_waitcnt vmcnt(8)" ::: "memory");
    } else {
      asm volatile("s_waitcnt vmcnt(0)" ::: "memory");
    }
    __builtin_amdgcn_s_barrier();
    i32x8 af[4], bfv[4];
#pragma unroll
    for (int i = 0; i < 4; ++i) {
      {
        const int row = wr * 64 + i * 16 + fr;
        const int r7 = row & 7;
        const unsigned char* rb = &As8[cur][row * 128];
        af[i] = mk8(*(const uint4*)(rb + (((2 * fq + 0) ^ r7) << 4)),
                    *(const uint4*)(rb + (((2 * fq + 1) ^ r7) << 4)));
      }
      {
        const int row = wc * 64 + i * 16 + fr;
        const int r7 = row & 7;
        const unsigned char* rb = &Bs8[cur][row * 128];
        bfv[i] = mk8(*(const uint4*)(rb + (((2 * fq + 0) ^ r7) << 4)),
                     *(const uint4*)(rb + (((2 * fq + 1) ^ r7) << 4)));
      }
    }
#pragma unroll
    for (int mi = 0; mi < 4; ++mi)
#pragma unroll
      for (int ni = 0; ni < 4; ++ni)
        acc[mi][ni] = MFMA16(af[mi], bfv[ni], acc[mi][ni]);
    asm volatile("s_waitcnt lgkmcnt(0)" ::: "memory");
    __builtin_amdgcn_s_barrier();
    __builtin_amdgcn_sched_barrier(0);
    cur ^= 1;
  }

  float ssq[4][4] = {};
#pragma unroll
  for (int mi = 0; mi < 4; ++mi)
#pragma unroll
    for (int ni = 0; ni < 4; ++ni)
#pragma unroll
      for (int r = 0; r < 4; ++r) {
        const int row = m0 + wr * 64 + mi * 16 + fq * 4 + r;
        const int col = o0 + wc * 64 + ni * 16 + fr;
        const float v = acc[mi][ni][r];
        Y8[(size_t)row * D_SZ + col] = f2fp8(v);
        ssq[mi][r] += v * v;
      }
#pragma unroll
  for (int mi = 0; mi < 4; ++mi)
#pragma unroll
    for (int r = 0; r < 4; ++r) {
      float v = ssq[mi][r];
      v += __shfl_xor(v, 1); v += __shfl_xor(v, 2);
      v += __shfl_xor(v, 4); v += __shfl_xor(v, 8);
      if (fr == 0) atomicAdd(&ssqG[m0 + wr * 64 + mi * 16 + fq * 4 + r], v);
    }
}

// ---------------------------------------------------------------------------
// Fold rne_n^3 into excT: excT'[l][n] = exc[n][l] ? (128/||y_n||)^3 : 0.
// ---------------------------------------------------------------------------
__global__ void excT_scale(unsigned char* __restrict__ excT8, const float* __restrict__ ssqE)
{
  const int n = blockIdx.x * 256 + threadIdx.x;
  if (n >= NP2) return;
  const float nrm = fmaxf(sqrtf(ssqE[n]), 1e-12f);
  const float iv = 128.0f / nrm;
  const unsigned char g8 = f2fp8(iv * iv * iv);
#pragma unroll
  for (int l = 0; l < L_SZ; ++l) {
    unsigned char* p = excT8 + (size_t)l * NP2 + n;
    *p = *p ? g8 : (unsigned char)0;
  }
}

// ---------------------------------------------------------------------------
// Fused s-GEMM (r13/r17 structure, proven 87 us / VGPR 116): swapped 32x32x64
// MFMA, in-register cube+shfl-exchange phase-2, counted vmcnt(8) dbuf,
// 8 tiles/block. Inputs UNNORMALIZED: epilogue cubes (dot/1024)^3; rne^3 is
// pre-folded into excT8, rf^3 applied in finalize.
// ---------------------------------------------------------------------------
__global__ __launch_bounds__(256, 1)
void echo_gemm8(const unsigned char* __restrict__ fn8,
                const unsigned char* __restrict__ exfn8,
                const unsigned char* __restrict__ excT8,
                float* __restrict__ echo)
{
  const int id = blockIdx.x;
  const int slot = id & 7, rest = id >> 3;
  const int m = rest & 7, xq = rest >> 3;
  const int x = xq * 8 + slot;
  if (x >= 49) return;
  const int m0 = m * 128;

  __shared__ __align__(16) unsigned char As8[2][128 * 128];  // exfn (n rows)
  __shared__ __align__(16) unsigned char Bs8[2][128 * 128];  // fn   (b rows)
  const int tid = threadIdx.x;
  const int w = tid >> 6, lane = tid & 63;
  const int nh = w >> 1, bh = w & 1;
  const int l31 = lane & 31, h = lane >> 5;
  const int srow = lane >> 3;
  const int schunk = (lane & 7) ^ srow;

  auto stage = [&](int buf, int n0s, int kk) {
#pragma unroll
    for (int i = 0; i < 4; ++i) {
      const int row = w * 32 + i * 8 + srow;
      GLOAD_LDS(exfn8 + (size_t)(n0s + row) * D_SZ + kk + schunk * 16,
                &As8[buf][(w * 32 + i * 8) * 128]);
      GLOAD_LDS(fn8 + (size_t)(m0 + row) * D_SZ + kk + schunk * 16,
                &Bs8[buf][(w * 32 + i * 8) * 128]);
    }
  };
  auto rdfrag = [&](const unsigned char* base, int row, int kh) -> i32x8 {
    const int r7 = row & 7;
    const unsigned char* rb = base + row * 128;
    return mk8(*(const uint4*)(rb + (((kh * 4 + h * 2 + 0) ^ r7) << 4)),
               *(const uint4*)(rb + (((kh * 4 + h * 2 + 1) ^ r7) << 4)));
  };

  f32x16 acc2[2] = {};
  int cur = 0;
  stage(0, x * 8 * 128, 0);

  for (int ti = 0; ti < 8; ++ti) {
    const int n0 = (x * 8 + ti) * 128;
    f32x16 acc[2][2] = {};   // [n-subtile t][b-subtile b2]
    for (int kk = 0; kk < D_SZ; kk += 128) {
      if (kk + 128 < D_SZ) {
        stage(cur ^ 1, n0, kk + 128);                    // 8 newer in flight
        asm volatile("s_waitcnt vmcnt(8)" ::: "memory"); // oldest 8 = cur done
      } else {
        asm volatile("s_waitcnt vmcnt(0)" ::: "memory");
      }
      __builtin_amdgcn_s_barrier();
#pragma unroll
      for (int kh = 0; kh < 2; ++kh) {
        i32x8 af0 = rdfrag(As8[cur], nh * 64 + l31, kh);
        i32x8 af1 = rdfrag(As8[cur], nh * 64 + 32 + l31, kh);
        i32x8 bf0 = rdfrag(Bs8[cur], bh * 64 + l31, kh);
        i32x8 bf1 = rdfrag(Bs8[cur], bh * 64 + 32 + l31, kh);
        __builtin_amdgcn_s_setprio(1);
        acc[0][0] = MFMA32(af0, bf0, acc[0][0]);
        acc[0][1] = MFMA32(af0, bf1, acc[0][1]);
        acc[1][0] = MFMA32(af1, bf0, acc[1][0]);
        acc[1][1] = MFMA32(af1, bf1, acc[1][1]);
        __builtin_amdgcn_s_setprio(0);
      }
      asm volatile("s_waitcnt lgkmcnt(0)" ::: "memory");
      __builtin_amdgcn_s_barrier();
      __builtin_amdgcn_sched_barrier(0);
      cur ^= 1;
    }
    // ---- epilogue: cube (x 1/1024) + in-reg exchange + phase-2 MFMA ----
#pragma unroll
    for (int b2 = 0; b2 < 2; ++b2) {
      unsigned frag[8];
#pragma unroll
      for (int q = 0; q < 4; ++q) {
        unsigned w0 = 0, w1 = 0;
#pragma unroll
        for (int i = 0; i < 4; ++i) {
          float v0 = acc[0][b2][4 * q + i] * (1.0f / 1024.0f);
          float v1 = acc[1][b2][4 * q + i] * (1.0f / 1024.0f);
          w0 |= (unsigned)f2fp8(v0 * v0 * v0) << (8 * i);
          w1 |= (unsigned)f2fp8(v1 * v1 * v1) << (8 * i);
        }
        const unsigned keep = h ? w1 : w0;   // my n-subtile t=h values
        const unsigned send = h ? w0 : w1;   // partner needs my t=1-h
        const unsigned recv = (unsigned)__shfl_xor((int)send, 32);
        frag[2 * q]     = h ? recv : keep;
        frag[2 * q + 1] = h ? keep : recv;
      }
      i32x8 pa;
#pragma unroll
      for (int k = 0; k < 8; ++k) pa[k] = (int)frag[k];
      const unsigned char* gp = excT8 + (size_t)l31 * NP2 + n0 + nh * 64 + h * 32;
      i32x8 pb = mk8(*(const uint4*)gp, *(const uint4*)(gp + 16));
      acc2[b2] = MFMA32(pa, pb, acc2[b2]);
    }
    if (ti + 1 < 8) stage(cur, n0 + 128, 0);  // next tile k0 after epilogue
  }
#pragma unroll
  for (int b2 = 0; b2 < 2; ++b2)
#pragma unroll
    for (int r = 0; r < 16; ++r) {
      const int b = m0 + bh * 64 + b2 * 32 + (r & 3) + 8 * (r >> 2) + 4 * h;
      if (l31 < L_SZ)
        atomicAdd(&echo[(size_t)b * L_SZ + l31], acc2[b2][r]);
    }
}

// ---------------------------------------------------------------------------
// Finalize: reduce count partials -> echo * rf_b^3 / counts -> neg_dists ->
// BCE loss. scale_b = 512 / ||y_b||^3.
// ---------------------------------------------------------------------------
__global__ __launch_bounds__(1024)
void finalize(const float* __restrict__ echo, const float* __restrict__ cpart,
              const float* __restrict__ ssqF,
              const float* __restrict__ labels, const float* __restrict__ creps,
              float* __restrict__ out)
{
  __shared__ float C[L_SZ * L_SZ];
  __shared__ float cnt[L_SZ];
  __shared__ float red[16];
  const int tid = threadIdx.x;
  if (tid < L_SZ * L_SZ) C[tid] = creps[tid];
  // counts: group g (=class l) of 32 lanes sums cpart[j][l] over j=0..783
  {
    const int g = tid >> 5, ln = tid & 31;
    if (g < L_SZ) {
      float c = 0.f;
      for (int j = ln; j < EXCT_BLK; j += 32) c += cpart[(size_t)j * L_SZ + g];
#pragma unroll
      for (int o = 16; o; o >>= 1) c += __shfl_xor(c, o, 32);
      if (ln == 0) cnt[g] = c;
    }
  }
  __syncthreads();
  const float nb = fmaxf(sqrtf(ssqF[tid]), 1e-12f);
  const float sb = 512.0f / (nb * nb * nb);
  float e[L_SZ];
#pragma unroll
  for (int l = 0; l < L_SZ; ++l) e[l] = echo[tid * L_SZ + l] * sb / cnt[l];
  float lsum = 0.f;
  for (int j = 0; j < L_SZ; ++j) {
    float d2 = 0.f;
#pragma unroll
    for (int l = 0; l < L_SZ; ++l) { const float df = e[l] - C[j * L_SZ + l]; d2 += df * df; }
    const float nd = -sqrtf(d2);
    out[1 + tid * L_SZ + j] = nd;
    const float y = labels[tid * L_SZ + j];
    const float sp = fmaxf(nd, 0.f) + log1pf(expf(-fabsf(nd)));
    lsum += sp - nd * y;
  }
#pragma unroll
  for (int o = 32; o; o >>= 1) lsum += __shfl_xor(lsum, o);
  if ((tid & 63) == 0) red[tid >> 6] = lsum;
  __syncthreads();
  if (tid < 16) {
    float v = red[tid];
#pragma unroll
    for (int o = 8; o; o >>= 1) v += __shfl_xor(v, o);
    if (tid == 0) out[0] = v * (1.0f / (B_SZ * L_SZ));
  }
}

extern "C" void kernel_launch(void* const* d_in, const int* in_sizes, int n_in,
                              void* d_out, int out_size, void* d_ws, size_t ws_size,
                              hipStream_t stream)
{
  (void)in_sizes; (void)n_in; (void)out_size;
  const float* features = (const float*)d_in[0];
  const float* labels   = (const float*)d_in[1];
  const float* W_g      = (const float*)d_in[2];
  const float* ex_feat  = (const float*)d_in[3];
  const float* ex_cls   = (const float*)d_in[4];
  const float* creps    = (const float*)d_in[5];
  float* out = (float*)d_out;

  const size_t OFF_EXFN8 = 0;                                   // NP2*768 = 38,535,168
  const size_t OFF_FN8   = OFF_EXFN8 + (size_t)NP2 * D_SZ;      // + 786,432
  const size_t OFF_EXCT8 = OFF_FN8 + (size_t)B_SZ * D_SZ;       // + 32*NP2 = 1,605,632
  const size_t OFF_X8E   = OFF_EXCT8 + (size_t)32 * NP2;        // + 38,535,168
  const size_t OFF_X8F   = OFF_X8E + (size_t)NP2 * D_SZ;        // + 786,432
  const size_t OFF_W8    = OFF_X8F + (size_t)B_SZ * D_SZ;       // + 589,824
  const size_t OFF_ECHO  = OFF_W8 + (size_t)D_SZ * D_SZ;        // + 114,688  (zeroed in conv_all)
  const size_t OFF_SSQE  = OFF_ECHO + (size_t)B_SZ * L_SZ * 4;  // + NP2*4 = 200,704 (zeroed)
  const size_t OFF_SSQF  = OFF_SSQE + (size_t)NP2 * 4;          // + 4,096 (zeroed; span = 319,488 B)
  const size_t OFF_CPART = OFF_SSQF + (size_t)B_SZ * 4;         // + 784*28*4 = 87,808
  const size_t NEED      = OFF_CPART + (size_t)EXCT_BLK * L_SZ * 4;  // ~81.3 MB
  if (ws_size < NEED) return;

  char* ws = (char*)d_ws;
  unsigned char* exfn8 = (unsigned char*)(ws + OFF_EXFN8);
  unsigned char* fn8   = (unsigned char*)(ws + OFF_FN8);
  unsigned char* excT8 = (unsigned char*)(ws + OFF_EXCT8);
  unsigned char* X8e   = (unsigned char*)(ws + OFF_X8E);
  unsigned char* X8f   = (unsigned char*)(ws + OFF_X8F);
  unsigned char* W8    = (unsigned char*)(ws + OFF_W8);
  float* echo   = (float*)(ws + OFF_ECHO);
  float* ssqE   = (float*)(ws + OFF_SSQE);
  float* ssqF   = (float*)(ws + OFF_SSQF);
  float* cpart  = (float*)(ws + OFF_CPART);

  // merged conversion + excT build + count partials + echo/ssq zeroing
  conv_all<<<dim3(CONV_BLK + EXCT_BLK + ZERO_BLK), 256, 0, stream>>>(
      ex_feat, features, W_g, X8e, X8f, W8, ex_cls, excT8, cpart,
      (uint4*)(ws + OFF_ECHO));

  // proj: y in [0,400) -> 8 feature tiles + 392 ex tiles (covers NP2 rows)
  proj_gemm8<<<dim3(8 * 6 * 50), 256, 0, stream>>>(X8f, X8e, W8, fn8, exfn8, ssqF, ssqE);

  // fold rne^3 into excT (replaces the normY pass)
  excT_scale<<<dim3(NP2 / 256), 256, 0, stream>>>(excT8, ssqE);

  // grid: id = (x%8) + 8*(m + 8*(x/8)), x in [0,49), m in [0,8)
  echo_gemm8<<<dim3(8 * 8 * 7), 256, 0, stream>>>(fn8, exfn8, excT8, echo);
  finalize<<<dim3(1), 1024, 0, stream>>>(echo, cpart, ssqF, labels, creps, out);
}

// Round 20
// 209.261 us; speedup vs baseline: 1.1693x; 1.0104x over previous
//
#include <hip/hip_runtime.h>

#define D_SZ 768
#define N_SZ 50000
#define L_SZ 28
#define B_SZ 1024
#define NP2  50176   // 392*128 (padded N); 392 tiles = 56 slabs x 7 tiles

#define CONV_BLK 19488   // (NP2 + B_SZ + D_SZ) * 96 / 256
#define EXCT_BLK 784     // NP2 / 64
#define ZERO_BLK 78      // 78 * 256 * 16 B = 319,488 B = echo+ssqE+ssqF span

typedef float f32x4 __attribute__((ext_vector_type(4)));
typedef float f32x16 __attribute__((ext_vector_type(16)));
typedef int i32x8 __attribute__((ext_vector_type(8)));

// byte-order-proof single fp8 e4m3 convert (both packed bytes equal)
__device__ __forceinline__ unsigned char f2fp8(float a) {
  unsigned r;
  asm("v_cvt_pk_fp8_f32 %0, %1, %2" : "=v"(r) : "v"(a), "v"(a));
  return (unsigned char)(r & 0xFF);
}
__device__ __forceinline__ unsigned pk4_fp8(float a, float b, float c, float d) {
  unsigned lo, hi;
  asm("v_cvt_pk_fp8_f32 %0, %1, %2" : "=v"(lo) : "v"(a), "v"(b));
  asm("v_cvt_pk_fp8_f32 %0, %1, %2" : "=v"(hi) : "v"(c), "v"(d));
  return (lo & 0xFFFFu) | (hi << 16);
}
__device__ __forceinline__ i32x8 mk8(uint4 lo, uint4 hi) {
  i32x8 r;
  r[0] = (int)lo.x; r[1] = (int)lo.y; r[2] = (int)lo.z; r[3] = (int)lo.w;
  r[4] = (int)hi.x; r[5] = (int)hi.y; r[6] = (int)hi.z; r[7] = (int)hi.w;
  return r;
}
#define MFMA16(a, b, c) \
  __builtin_amdgcn_mfma_scale_f32_16x16x128_f8f6f4((a), (b), (c), 0, 0, \
                                                   0, 0x7F7F7F7F, 0, 0x7F7F7F7F)
#define MFMA32(a, b, c) \
  __builtin_amdgcn_mfma_scale_f32_32x32x64_f8f6f4((a), (b), (c), 0, 0, \
                                                  0, 0x7F7F7F7F, 0, 0x7F7F7F7F)
#define GLOAD_LDS(g, l) \
  __builtin_amdgcn_global_load_lds((const __attribute__((address_space(1))) void*)(g), \
                                   (__attribute__((address_space(3))) void*)(l), 16, 0, 0)

// ---------------------------------------------------------------------------
// Merged prep: [0, CONV_BLK) f32->fp8 conversion (ex +pad-zero, feat, W x8);
// [CONV_BLK, +EXCT_BLK) excT fp8 + per-block count partials (race-free);
// [CONV_BLK+EXCT_BLK, +ZERO_BLK) zero echo/ssqE/ssqF.
// ---------------------------------------------------------------------------
__global__ void conv_all(const float* __restrict__ ex, const float* __restrict__ feat,
                         const float* __restrict__ Wg,
                         unsigned char* __restrict__ X8e, unsigned char* __restrict__ X8f,
                         unsigned char* __restrict__ W8,
                         const float* __restrict__ exc, unsigned char* __restrict__ excT8,
                         float* __restrict__ cpart, uint4* __restrict__ zspan)
{
  __shared__ float lds[64][29];
  const int b = blockIdx.x;
  const int tid = threadIdx.x;
  if (b >= CONV_BLK + EXCT_BLK) {
    zspan[(b - CONV_BLK - EXCT_BLK) * 256 + tid] = make_uint4(0u, 0u, 0u, 0u);
    return;
  }
  if (b >= CONV_BLK) {
    const int j = b - CONV_BLK;
    const int n0 = j * 64;
    for (int i = tid; i < 64 * L_SZ; i += 256) {
      const int n = i / L_SZ, l = i % L_SZ;
      lds[n][l] = (n0 + n < N_SZ) ? exc[(size_t)(n0 + n) * L_SZ + l] : 0.0f;
    }
    __syncthreads();
    if (tid < L_SZ) {
      float c = 0.f;
      for (int n = 0; n < 64; ++n) c += lds[n][tid];
      cpart[(size_t)j * L_SZ + tid] = c;   // unconditional write, no init needed
    }
    for (int i = tid; i < 32 * 64; i += 256) {
      const int l = i >> 6, n = i & 63;
      excT8[(size_t)l * NP2 + n0 + n] = (l < L_SZ && lds[n][l] != 0.0f) ? 0x38 : 0x00;
    }
    return;
  }
  const int T_EX = NP2 * 96, T_EXV = N_SZ * 96, T_F = B_SZ * 96;
  const int t = b * 256 + tid;
  const float* src; unsigned char* dst; float scale; int u;
  if (t < T_EX) {
    if (t >= T_EXV) { *(uint2*)(X8e + (size_t)t * 8) = make_uint2(0u, 0u); return; }
    src = ex; dst = X8e; scale = 1.0f; u = t;
  } else if (t < T_EX + T_F) {
    src = feat; dst = X8f; scale = 1.0f; u = t - T_EX;
  } else {
    src = Wg; dst = W8; scale = 8.0f; u = t - T_EX - T_F;
  }
  const float4 a0 = *(const float4*)(src + (size_t)u * 8);
  const float4 a1 = *(const float4*)(src + (size_t)u * 8 + 4);
  uint2 o;
  o.x = pk4_fp8(a0.x * scale, a0.y * scale, a0.z * scale, a0.w * scale);
  o.y = pk4_fp8(a1.x * scale, a1.y * scale, a1.z * scale, a1.w * scale);
  *(uint2*)(dst + (size_t)u * 8) = o;
}

// ---------------------------------------------------------------------------
// Projection GEMM, fp8 K=128 (round-10/13 proven, unchanged). Unnormalized
// fp8 Y + exact per-row ssq (f32 acc) via atomics. Co-XCD y-swizzle.
// ---------------------------------------------------------------------------
__global__ __launch_bounds__(256, 2)
void proj_gemm8(const unsigned char* __restrict__ Xf8,
                const unsigned char* __restrict__ Xe8,
                const unsigned char* __restrict__ W8,
                unsigned char* __restrict__ Yf8, unsigned char* __restrict__ Ye8,
                float* __restrict__ ssqF, float* __restrict__ ssqE)
{
  const int id = blockIdx.x;
  const int slot = id & 7, rest = id >> 3;
  const int x = rest % 6, yq = rest / 6;
  const int y = yq * 8 + slot;   // y in [0,400): 8 feature tiles + 392 ex tiles

  __shared__ __align__(16) unsigned char As8[2][128 * 128];
  __shared__ __align__(16) unsigned char Bs8[2][128 * 128];
  const int tid = threadIdx.x;
  const int w = tid >> 6, lane = tid & 63;
  const int wr = w >> 1, wc = w & 1;
  const int fr = lane & 15, fq = lane >> 4;
  const int srow = lane >> 3;
  const int schunk = (lane & 7) ^ srow;
  const int o0 = x * 128;

  const unsigned char* Xb; unsigned char* Y8; float* ssqG; int m0;
  if (y < 8) { Xb = Xf8; Y8 = Yf8; ssqG = ssqF; m0 = y * 128; }
  else       { Xb = Xe8; Y8 = Ye8; ssqG = ssqE; m0 = (y - 8) * 128; }

  auto stage = [&](int buf, int kk) {
#pragma unroll
    for (int i = 0; i < 4; ++i) {
      const int row = w * 32 + i * 8 + srow;
      GLOAD_LDS(Xb + (size_t)(m0 + row) * D_SZ + kk + schunk * 16,
                &As8[buf][(w * 32 + i * 8) * 128]);
      GLOAD_LDS(W8 + (size_t)(o0 + row) * D_SZ + kk + schunk * 16,
                &Bs8[buf][(w * 32 + i * 8) * 128]);
    }
  };

  f32x4 acc[4][4] = {};
  int cur = 0;
  stage(0, 0);

  for (int kk = 0; kk < D_SZ; kk += 128) {
    if (kk + 128 < D_SZ) {
      stage(cur ^ 1, kk + 128);
      asm volatile("s_waitcnt vmcnt(8)" ::: "memory");
    } else {
      asm volatile("s_waitcnt vmcnt(0)" ::: "memory");
    }
    __builtin_amdgcn_s_barrier();
    i32x8 af[4], bfv[4];
#pragma unroll
    for (int i = 0; i < 4; ++i) {
      {
        const int row = wr * 64 + i * 16 + fr;
        const int r7 = row & 7;
        const unsigned char* rb = &As8[cur][row * 128];
        af[i] = mk8(*(const uint4*)(rb + (((2 * fq + 0) ^ r7) << 4)),
                    *(const uint4*)(rb + (((2 * fq + 1) ^ r7) << 4)));
      }
      {
        const int row = wc * 64 + i * 16 + fr;
        const int r7 = row & 7;
        const unsigned char* rb = &Bs8[cur][row * 128];
        bfv[i] = mk8(*(const uint4*)(rb + (((2 * fq + 0) ^ r7) << 4)),
                     *(const uint4*)(rb + (((2 * fq + 1) ^ r7) << 4)));
      }
    }
#pragma unroll
    for (int mi = 0; mi < 4; ++mi)
#pragma unroll
      for (int ni = 0; ni < 4; ++ni)
        acc[mi][ni] = MFMA16(af[mi], bfv[ni], acc[mi][ni]);
    asm volatile("s_waitcnt lgkmcnt(0)" ::: "memory");
    __builtin_amdgcn_s_barrier();
    __builtin_amdgcn_sched_barrier(0);
    cur ^= 1;
  }

  float ssq[4][4] = {};
#pragma unroll
  for (int mi = 0; mi < 4; ++mi)
#pragma unroll
    for (int ni = 0; ni < 4; ++ni)
#pragma unroll
      for (int r = 0; r < 4; ++r) {
        const int row = m0 + wr * 64 + mi * 16 + fq * 4 + r;
        const int col = o0 + wc * 64 + ni * 16 + fr;
        const float v = acc[mi][ni][r];
        Y8[(size_t)row * D_SZ + col] = f2fp8(v);
        ssq[mi][r] += v * v;
      }
#pragma unroll
  for (int mi = 0; mi < 4; ++mi)
#pragma unroll
    for (int r = 0; r < 4; ++r) {
      float v = ssq[mi][r];
      v += __shfl_xor(v, 1); v += __shfl_xor(v, 2);
      v += __shfl_xor(v, 4); v += __shfl_xor(v, 8);
      if (fr == 0) atomicAdd(&ssqG[m0 + wr * 64 + mi * 16 + fq * 4 + r], v);
    }
}

// ---------------------------------------------------------------------------
// Fold rne_n^3 into excT: excT'[l][n] = exc[n][l] ? (128/||y_n||)^3 : 0.
// ---------------------------------------------------------------------------
__global__ void excT_scale(unsigned char* __restrict__ excT8, const float* __restrict__ ssqE)
{
  const int n = blockIdx.x * 256 + threadIdx.x;
  if (n >= NP2) return;
  const float nrm = fmaxf(sqrtf(ssqE[n]), 1e-12f);
  const float iv = 128.0f / nrm;
  const unsigned char g8 = f2fp8(iv * iv * iv);
#pragma unroll
  for (int l = 0; l < L_SZ; ++l) {
    unsigned char* p = excT8 + (size_t)l * NP2 + n;
    *p = *p ? g8 : (unsigned char)0;
  }
}

// ---------------------------------------------------------------------------
// Fused s-GEMM (r13 pipeline): swapped 32x32x64 MFMA, in-register
// cube+shfl-exchange phase-2, counted vmcnt(8) dbuf, unnormalized inputs.
// ROUND-20: 56 slabs x 7 tiles (= 392 exactly) -> all 448 blocks do work
// (the old 49x8 grid had 56 no-op blocks; critical-path CUs ran 2x8=16
// tiles, now 2x7=14). Co-XCD: slab's 8 m-sharers keep id%8 = x%8;
// slab = 7x128x768 = 688 KB << 4 MB L2.
// ---------------------------------------------------------------------------
__global__ __launch_bounds__(256, 1)
void echo_gemm8(const unsigned char* __restrict__ fn8,
                const unsigned char* __restrict__ exfn8,
                const unsigned char* __restrict__ excT8,
                float* __restrict__ echo)
{
  const int id = blockIdx.x;
  const int slot = id & 7, rest = id >> 3;
  const int m = rest & 7, xq = rest >> 3;
  const int x = xq * 8 + slot;          // x in [0,56), all valid
  const int m0 = m * 128;

  __shared__ __align__(16) unsigned char As8[2][128 * 128];  // exfn (n rows)
  __shared__ __align__(16) unsigned char Bs8[2][128 * 128];  // fn   (b rows)
  const int tid = threadIdx.x;
  const int w = tid >> 6, lane = tid & 63;
  const int nh = w >> 1, bh = w & 1;
  const int l31 = lane & 31, h = lane >> 5;
  const int srow = lane >> 3;
  const int schunk = (lane & 7) ^ srow;

  auto stage = [&](int buf, int n0s, int kk) {
#pragma unroll
    for (int i = 0; i < 4; ++i) {
      const int row = w * 32 + i * 8 + srow;
      GLOAD_LDS(exfn8 + (size_t)(n0s + row) * D_SZ + kk + schunk * 16,
                &As8[buf][(w * 32 + i * 8) * 128]);
      GLOAD_LDS(fn8 + (size_t)(m0 + row) * D_SZ + kk + schunk * 16,
                &Bs8[buf][(w * 32 + i * 8) * 128]);
    }
  };
  auto rdfrag = [&](const unsigned char* base, int row, int kh) -> i32x8 {
    const int r7 = row & 7;
    const unsigned char* rb = base + row * 128;
    return mk8(*(const uint4*)(rb + (((kh * 4 + h * 2 + 0) ^ r7) << 4)),
               *(const uint4*)(rb + (((kh * 4 + h * 2 + 1) ^ r7) << 4)));
  };

  f32x16 acc2[2] = {};
  int cur = 0;
  stage(0, x * 7 * 128, 0);

  for (int ti = 0; ti < 7; ++ti) {
    const int n0 = (x * 7 + ti) * 128;
    f32x16 acc[2][2] = {};   // [n-subtile t][b-subtile b2]
    for (int kk = 0; kk < D_SZ; kk += 128) {
      if (kk + 128 < D_SZ) {
        stage(cur ^ 1, n0, kk + 128);                    // 8 newer in flight
        asm volatile("s_waitcnt vmcnt(8)" ::: "memory"); // oldest 8 = cur done
      } else {
        asm volatile("s_waitcnt vmcnt(0)" ::: "memory");
      }
      __builtin_amdgcn_s_barrier();
#pragma unroll
      for (int kh = 0; kh < 2; ++kh) {
        i32x8 af0 = rdfrag(As8[cur], nh * 64 + l31, kh);
        i32x8 af1 = rdfrag(As8[cur], nh * 64 + 32 + l31, kh);
        i32x8 bf0 = rdfrag(Bs8[cur], bh * 64 + l31, kh);
        i32x8 bf1 = rdfrag(Bs8[cur], bh * 64 + 32 + l31, kh);
        __builtin_amdgcn_s_setprio(1);
        acc[0][0] = MFMA32(af0, bf0, acc[0][0]);
        acc[0][1] = MFMA32(af0, bf1, acc[0][1]);
        acc[1][0] = MFMA32(af1, bf0, acc[1][0]);
        acc[1][1] = MFMA32(af1, bf1, acc[1][1]);
        __builtin_amdgcn_s_setprio(0);
      }
      asm volatile("s_waitcnt lgkmcnt(0)" ::: "memory");
      __builtin_amdgcn_s_barrier();
      __builtin_amdgcn_sched_barrier(0);
      cur ^= 1;
    }
    // ---- epilogue: cube (x 1/1024) + in-reg exchange + phase-2 MFMA ----
#pragma unroll
    for (int b2 = 0; b2 < 2; ++b2) {
      unsigned frag[8];
#pragma unroll
      for (int q = 0; q < 4; ++q) {
        unsigned w0 = 0, w1 = 0;
#pragma unroll
        for (int i = 0; i < 4; ++i) {
          float v0 = acc[0][b2][4 * q + i] * (1.0f / 1024.0f);
          float v1 = acc[1][b2][4 * q + i] * (1.0f / 1024.0f);
          w0 |= (unsigned)f2fp8(v0 * v0 * v0) << (8 * i);
          w1 |= (unsigned)f2fp8(v1 * v1 * v1) << (8 * i);
        }
        const unsigned keep = h ? w1 : w0;   // my n-subtile t=h values
        const unsigned send = h ? w0 : w1;   // partner needs my t=1-h
        const unsigned recv = (unsigned)__shfl_xor((int)send, 32);
        frag[2 * q]     = h ? recv : keep;
        frag[2 * q + 1] = h ? keep : recv;
      }
      i32x8 pa;
#pragma unroll
      for (int k = 0; k < 8; ++k) pa[k] = (int)frag[k];
      const unsigned char* gp = excT8 + (size_t)l31 * NP2 + n0 + nh * 64 + h * 32;
      i32x8 pb = mk8(*(const uint4*)gp, *(const uint4*)(gp + 16));
      acc2[b2] = MFMA32(pa, pb, acc2[b2]);
    }
    if (ti + 1 < 7) stage(cur, n0 + 128, 0);  // next tile k0 after epilogue
  }
#pragma unroll
  for (int b2 = 0; b2 < 2; ++b2)
#pragma unroll
    for (int r = 0; r < 16; ++r) {
      const int b = m0 + bh * 64 + b2 * 32 + (r & 3) + 8 * (r >> 2) + 4 * h;
      if (l31 < L_SZ)
        atomicAdd(&echo[(size_t)b * L_SZ + l31], acc2[b2][r]);
    }
}

// ---------------------------------------------------------------------------
// Finalize: reduce count partials -> echo * rf_b^3 / counts -> neg_dists ->
// BCE loss. scale_b = 512 / ||y_b||^3.
// ---------------------------------------------------------------------------
__global__ __launch_bounds__(1024)
void finalize(const float* __restrict__ echo, const float* __restrict__ cpart,
              const float* __restrict__ ssqF,
              const float* __restrict__ labels, const float* __restrict__ creps,
              float* __restrict__ out)
{
  __shared__ float C[L_SZ * L_SZ];
  __shared__ float cnt[L_SZ];
  __shared__ float red[16];
  const int tid = threadIdx.x;
  if (tid < L_SZ * L_SZ) C[tid] = creps[tid];
  // counts: group g (=class l) of 32 lanes sums cpart[j][l] over j=0..783
  {
    const int g = tid >> 5, ln = tid & 31;
    if (g < L_SZ) {
      float c = 0.f;
      for (int j = ln; j < EXCT_BLK; j += 32) c += cpart[(size_t)j * L_SZ + g];
#pragma unroll
      for (int o = 16; o; o >>= 1) c += __shfl_xor(c, o, 32);
      if (ln == 0) cnt[g] = c;
    }
  }
  __syncthreads();
  const float nb = fmaxf(sqrtf(ssqF[tid]), 1e-12f);
  const float sb = 512.0f / (nb * nb * nb);
  float e[L_SZ];
#pragma unroll
  for (int l = 0; l < L_SZ; ++l) e[l] = echo[tid * L_SZ + l] * sb / cnt[l];
  float lsum = 0.f;
  for (int j = 0; j < L_SZ; ++j) {
    float d2 = 0.f;
#pragma unroll
    for (int l = 0; l < L_SZ; ++l) { const float df = e[l] - C[j * L_SZ + l]; d2 += df * df; }
    const float nd = -sqrtf(d2);
    out[1 + tid * L_SZ + j] = nd;
    const float y = labels[tid * L_SZ + j];
    const float sp = fmaxf(nd, 0.f) + log1pf(expf(-fabsf(nd)));
    lsum += sp - nd * y;
  }
#pragma unroll
  for (int o = 32; o; o >>= 1) lsum += __shfl_xor(lsum, o);
  if ((tid & 63) == 0) red[tid >> 6] = lsum;
  __syncthreads();
  if (tid < 16) {
    float v = red[tid];
#pragma unroll
    for (int o = 8; o; o >>= 1) v += __shfl_xor(v, o);
    if (tid == 0) out[0] = v * (1.0f / (B_SZ * L_SZ));
  }
}

extern "C" void kernel_launch(void* const* d_in, const int* in_sizes, int n_in,
                              void* d_out, int out_size, void* d_ws, size_t ws_size,
                              hipStream_t stream)
{
  (void)in_sizes; (void)n_in; (void)out_size;
  const float* features = (const float*)d_in[0];
  const float* labels   = (const float*)d_in[1];
  const float* W_g      = (const float*)d_in[2];
  const float* ex_feat  = (const float*)d_in[3];
  const float* ex_cls   = (const float*)d_in[4];
  const float* creps    = (const float*)d_in[5];
  float* out = (float*)d_out;

  const size_t OFF_EXFN8 = 0;                                   // NP2*768 = 38,535,168
  const size_t OFF_FN8   = OFF_EXFN8 + (size_t)NP2 * D_SZ;      // + 786,432
  const size_t OFF_EXCT8 = OFF_FN8 + (size_t)B_SZ * D_SZ;       // + 32*NP2 = 1,605,632
  const size_t OFF_X8E   = OFF_EXCT8 + (size_t)32 * NP2;        // + 38,535,168
  const size_t OFF_X8F   = OFF_X8E + (size_t)NP2 * D_SZ;        // + 786,432
  const size_t OFF_W8    = OFF_X8F + (size_t)B_SZ * D_SZ;       // + 589,824
  const size_t OFF_ECHO  = OFF_W8 + (size_t)D_SZ * D_SZ;        // + 114,688  (zeroed in conv_all)
  const size_t OFF_SSQE  = OFF_ECHO + (size_t)B_SZ * L_SZ * 4;  // + NP2*4 = 200,704 (zeroed)
  const size_t OFF_SSQF  = OFF_SSQE + (size_t)NP2 * 4;          // + 4,096 (zeroed; span = 319,488 B)
  const size_t OFF_CPART = OFF_SSQF + (size_t)B_SZ * 4;         // + 784*28*4 = 87,808
  const size_t NEED      = OFF_CPART + (size_t)EXCT_BLK * L_SZ * 4;  // ~81.3 MB
  if (ws_size < NEED) return;

  char* ws = (char*)d_ws;
  unsigned char* exfn8 = (unsigned char*)(ws + OFF_EXFN8);
  unsigned char* fn8   = (unsigned char*)(ws + OFF_FN8);
  unsigned char* excT8 = (unsigned char*)(ws + OFF_EXCT8);
  unsigned char* X8e   = (unsigned char*)(ws + OFF_X8E);
  unsigned char* X8f   = (unsigned char*)(ws + OFF_X8F);
  unsigned char* W8    = (unsigned char*)(ws + OFF_W8);
  float* echo   = (float*)(ws + OFF_ECHO);
  float* ssqE   = (float*)(ws + OFF_SSQE);
  float* ssqF   = (float*)(ws + OFF_SSQF);
  float* cpart  = (float*)(ws + OFF_CPART);

  // merged conversion + excT build + count partials + echo/ssq zeroing
  conv_all<<<dim3(CONV_BLK + EXCT_BLK + ZERO_BLK), 256, 0, stream>>>(
      ex_feat, features, W_g, X8e, X8f, W8, ex_cls, excT8, cpart,
      (uint4*)(ws + OFF_ECHO));

  // proj: y in [0,400) -> 8 feature tiles + 392 ex tiles (covers NP2 rows)
  proj_gemm8<<<dim3(8 * 6 * 50), 256, 0, stream>>>(X8f, X8e, W8, fn8, exfn8, ssqF, ssqE);

  // fold rne^3 into excT (replaces the normY pass)
  excT_scale<<<dim3(NP2 / 256), 256, 0, stream>>>(excT8, ssqE);

  // grid: id = (x%8) + 8*(m + 8*(x/8)), x in [0,56), m in [0,8); all valid
  echo_gemm8<<<dim3(8 * 8 * 7), 256, 0, stream>>>(fn8, exfn8, excT8, echo);
  finalize<<<dim3(1), 1024, 0, stream>>>(echo, cpart, ssqF, labels, creps, out);
}